// Round 5
// baseline (7004.563 us; speedup 1.0000x reference)
//
#include <hip/hip_runtime.h>
#include <math.h>

typedef _Float16 f16;

#define NB 4
#define NT 20000
#define NN 60000
#define HD 128

__device__ __forceinline__ float gelu_f(float t){
    return 0.5f*t*(1.0f+erff(t*0.70710678118654752f));
}

// ---------- P1: inflate. 2 rows per 256-thread block.
// v1[row,col] = vertf[row,col] + b_inf[col] + sum_{slot,k} mask*hexf[b,idx,k]*W_inf[slot*128+k, col]
template<bool F32V1>
__global__ __launch_bounds__(256) void p_inflate(
    const float* __restrict__ hexf, const float* __restrict__ vertf,
    const int* __restrict__ v2h, const float* __restrict__ W_inf,
    const float* __restrict__ b_inf, float* __restrict__ v1f, f16* __restrict__ v1h)
{
    const int col = threadIdx.x & 127;
    const int row = blockIdx.x*2 + (threadIdx.x>>7);
    const int b = row / NN, n = row - b*NN;
    float acc = b_inf[col];
    for (int slot=0; slot<3; ++slot){
        const int idx = v2h[n*3+slot];
        if (idx >= 0){
            const float* hp = hexf + (long)(b*NT+idx)*HD;
            const float* wp = W_inf + (long)(slot*HD)*HD + col;
            for (int k=0;k<HD;++k) acc += hp[k]*wp[(long)k*HD];
        }
    }
    const long a = (long)row*HD + col;
    const float v = acc + vertf[a];
    if (F32V1) v1f[a] = v; else v1h[a] = (f16)v;
}

// ---------- P2: message pass + update + LN. One row per 128-thread block.
template<bool F32V1>
__global__ __launch_bounds__(128) void p_vertex_a(
    const float* __restrict__ v1f, const f16* __restrict__ v1h,
    const int* __restrict__ vadj,
    const float* __restrict__ W_msg, const float* __restrict__ b_msg,
    const float* __restrict__ W_upd, const float* __restrict__ b_upd,
    const float* __restrict__ vng, const float* __restrict__ vnb,
    float* __restrict__ vout)
{
    __shared__ float s[HD], sv[HD], agg[HD], red[HD];
    const int col = threadIdx.x;
    const int row = blockIdx.x;
    const int b = row / NN, n = row - b*NN;
    float ssum = 0.f; int cnt = 0;
    for (int j=0;j<3;++j){
        const int idx = vadj[n*3+j];
        if (idx>=0){
            cnt++;
            ssum += F32V1 ? v1f[(long)(b*NN+idx)*HD+col] : (float)v1h[(long)(b*NN+idx)*HD+col];
        }
    }
    s[col] = ssum;
    sv[col] = F32V1 ? v1f[(long)row*HD+col] : (float)v1h[(long)row*HD+col];
    __syncthreads();
    const float ic = 1.0f/(float)(cnt<1?1:cnt);
    float m = 0.f;
    for (int k=0;k<HD;++k) m += s[k]*W_msg[(long)k*HD+col];
    agg[col] = (m + 3.0f*b_msg[col])*ic;   // bias added to all 3 slots incl. masked, / valid-cnt
    __syncthreads();
    float u = b_upd[col] + sv[col];        // mp_out + residual (pre-LN)
    for (int k=0;k<HD;++k) u += sv[k]*W_upd[(long)k*HD+col];
    for (int k=0;k<HD;++k) u += agg[k]*W_upd[(long)(HD+k)*HD+col];
    red[col] = u; __syncthreads();
    float mu=0.f;
    for (int k=0;k<HD;++k) mu += red[k];
    mu *= (1.f/HD);
    float var=0.f;
    for (int k=0;k<HD;++k){ const float d=red[k]-mu; var += d*d; }
    var *= (1.f/HD);
    vout[(long)row*HD+col] = (u-mu)*rsqrtf(var+1e-5f)*vng[col] + vnb[col];
}

// ---------- P3: residual MLP, in-place on io. One row per 256-thread block.
// io[row] = x + gelu(x@W1 + b1)@W2 + b2, W1:(128,256) W2:(256,128)
__global__ __launch_bounds__(256) void p_mlp(
    float* __restrict__ io, const float* __restrict__ W1, const float* __restrict__ b1,
    const float* __restrict__ W2, const float* __restrict__ b2)
{
    __shared__ float x[HD], h[2*HD];
    const int t = threadIdx.x;
    const long row = blockIdx.x;
    if (t < HD) x[t] = io[row*HD + t];
    __syncthreads();
    float a = b1[t];
    for (int k=0;k<HD;++k) a += x[k]*W1[(long)k*2*HD + t];
    h[t] = gelu_f(a);
    __syncthreads();
    if (t < HD){
        float y = x[t] + b2[t];
        for (int k=0;k<2*HD;++k) y += h[k]*W2[(long)k*HD + t];
        io[row*HD + t] = y;
    }
}

// ---------- P4: deflate (masked mean of 6) + W_def + LN. One hex row per 128-thread block.
__global__ __launch_bounds__(128) void p_hex_a(
    const float* __restrict__ hexf, const float* __restrict__ vfin,
    const int* __restrict__ h2v,
    const float* __restrict__ W_def, const float* __restrict__ b_def,
    const float* __restrict__ hng, const float* __restrict__ hnb,
    float* __restrict__ hout)
{
    __shared__ float p[HD], red[HD];
    const int col = threadIdx.x;
    const int row = blockIdx.x;
    const int b = row / NT, t = row - b*NT;
    float ssum=0.f; int cnt=0;
    for (int j=0;j<6;++j){
        const int idx = h2v[t*6+j];
        if (idx>=0){ cnt++; ssum += vfin[(long)(b*NN+idx)*HD+col]; }
    }
    p[col] = ssum * (1.0f/(float)(cnt<1?1:cnt));
    __syncthreads();
    float u = b_def[col] + hexf[(long)row*HD+col];
    for (int k=0;k<HD;++k) u += p[k]*W_def[(long)k*HD+col];
    red[col]=u; __syncthreads();
    float mu=0.f;
    for (int k=0;k<HD;++k) mu += red[k];
    mu*=(1.f/HD);
    float var=0.f;
    for (int k=0;k<HD;++k){ const float d=red[k]-mu; var+=d*d; }
    var*=(1.f/HD);
    hout[(long)row*HD+col] = (u-mu)*rsqrtf(var+1e-5f)*hng[col] + hnb[col];
}

extern "C" void kernel_launch(void* const* d_in, const int* in_sizes, int n_in,
                              void* d_out, int out_size, void* d_ws, size_t ws_size,
                              hipStream_t stream)
{
    (void)in_sizes; (void)n_in; (void)out_size;
    const float* hexf  = (const float*)d_in[0];
    const float* vertf = (const float*)d_in[1];
    const float* W_inf = (const float*)d_in[2];
    const float* b_inf = (const float*)d_in[3];
    const float* W_msg = (const float*)d_in[4];
    const float* b_msg = (const float*)d_in[5];
    const float* W_upd = (const float*)d_in[6];
    const float* b_upd = (const float*)d_in[7];
    const float* W_def = (const float*)d_in[8];
    const float* b_def = (const float*)d_in[9];
    const float* vng   = (const float*)d_in[10];
    const float* vnb   = (const float*)d_in[11];
    const float* hng   = (const float*)d_in[12];
    const float* hnb   = (const float*)d_in[13];
    const float* Wv1   = (const float*)d_in[14];
    const float* bv1   = (const float*)d_in[15];
    const float* Wv2   = (const float*)d_in[16];
    const float* bv2   = (const float*)d_in[17];
    const float* Wh1   = (const float*)d_in[18];
    const float* bh1   = (const float*)d_in[19];
    const float* Wh2   = (const float*)d_in[20];
    const float* bh2   = (const float*)d_in[21];
    const int* v2h   = (const int*)d_in[22];
    const int* h2v   = (const int*)d_in[23];
    const int* vadj  = (const int*)d_in[24];

    const long NV = (long)NB*NN;                 // 240000 vertex rows
    const size_t v1f_bytes = (size_t)NV*HD*4;    // 122.88 MB
    const bool f32v1 = (ws_size >= v1f_bytes);

    float* v1f = (float*)d_ws;
    f16*   v1h = (f16*)d_ws;

    float* hout = (float*)d_out;
    float* vout = hout + (long)NB*NT*HD;

    if (f32v1){
        p_inflate<true><<<120000,256,0,stream>>>(hexf, vertf, v2h, W_inf, b_inf, v1f, v1h);
        p_vertex_a<true><<<240000,128,0,stream>>>(v1f, v1h, vadj, W_msg, b_msg, W_upd, b_upd,
                                                  vng, vnb, vout);
    } else {
        p_inflate<false><<<120000,256,0,stream>>>(hexf, vertf, v2h, W_inf, b_inf, v1f, v1h);
        p_vertex_a<false><<<240000,128,0,stream>>>(v1f, v1h, vadj, W_msg, b_msg, W_upd, b_upd,
                                                   vng, vnb, vout);
    }
    p_mlp<<<240000,256,0,stream>>>(vout, Wv1, bv1, Wv2, bv2);
    p_hex_a<<<80000,128,0,stream>>>(hexf, vout, h2v, W_def, b_def, hng, hnb, hout);
    p_mlp<<<80000,256,0,stream>>>(hout, Wh1, bh1, Wh2, bh2);
}

// Round 7
// 6448.059 us; speedup vs baseline: 1.0863x; 1.0863x over previous
//
#include <hip/hip_runtime.h>
#include <math.h>

typedef _Float16 f16;
typedef __attribute__((ext_vector_type(8))) _Float16 f16x8;
typedef __attribute__((ext_vector_type(4))) float f32x4;
typedef __attribute__((ext_vector_type(2))) float f32x2;

#define NB 4
#define NT 20000
#define NN 60000
#define HD 128

#define MFMA(a,b,c) __builtin_amdgcn_mfma_f32_16x16x32_f16((a),(b),(c),0,0,0)

__device__ __forceinline__ float gelu_f(float t){
    return 0.5f*t*(1.0f+erff(t*0.70710678118654752f));
}

// Pack weight W (K x Nc, row-major, f32) into f16 MFMA B-frag order:
// dst[((kb*NCT+ct)*64+lane)*8 + j] = f16(W[kb*32+(lane>>4)*8+j][ct*16+(lane&15)])
__global__ void k_pack(const float* __restrict__ src, f16* __restrict__ dst, int K, int Nc){
    int e = blockIdx.x*256 + threadIdx.x;
    if (e >= K*Nc) return;
    int j = e & 7;
    int lane = (e>>3) & 63;
    int tile = e >> 9;
    int nct = Nc >> 4;
    int ct = tile % nct;
    int kb = tile / nct;
    int k = kb*32 + ((lane>>4)<<3) + j;
    int n = ct*16 + (lane&15);
    dst[e] = (f16)src[k*Nc + n];
}

// ---------- P1 (verified): inflate. 2 rows per 256-thread block.
template<bool F32V1>
__global__ __launch_bounds__(256) void p_inflate(
    const float* __restrict__ hexf, const float* __restrict__ vertf,
    const int* __restrict__ v2h, const float* __restrict__ W_inf,
    const float* __restrict__ b_inf, float* __restrict__ v1f, f16* __restrict__ v1h)
{
    const int col = threadIdx.x & 127;
    const int row = blockIdx.x*2 + (threadIdx.x>>7);
    const int b = row / NN, n = row - b*NN;
    float acc = b_inf[col];
    for (int slot=0; slot<3; ++slot){
        const int idx = v2h[n*3+slot];
        if (idx >= 0){
            const float* hp = hexf + (long)(b*NT+idx)*HD;
            const float* wp = W_inf + (long)(slot*HD)*HD + col;
            for (int k=0;k<HD;++k) acc += hp[k]*wp[(long)k*HD];
        }
    }
    const long a = (long)row*HD + col;
    const float v = acc + vertf[a];
    if (F32V1) v1f[a] = v; else v1h[a] = (f16)v;
}

// ---------- P2 (verified): message pass + update + LN. One row per 128-thread block.
template<bool F32V1>
__global__ __launch_bounds__(128) void p_vertex_a(
    const float* __restrict__ v1f, const f16* __restrict__ v1h,
    const int* __restrict__ vadj,
    const float* __restrict__ W_msg, const float* __restrict__ b_msg,
    const float* __restrict__ W_upd, const float* __restrict__ b_upd,
    const float* __restrict__ vng, const float* __restrict__ vnb,
    float* __restrict__ vout)
{
    __shared__ float s[HD], sv[HD], agg[HD], red[HD];
    const int col = threadIdx.x;
    const int row = blockIdx.x;
    const int b = row / NN, n = row - b*NN;
    float ssum = 0.f; int cnt = 0;
    for (int j=0;j<3;++j){
        const int idx = vadj[n*3+j];
        if (idx>=0){
            cnt++;
            ssum += F32V1 ? v1f[(long)(b*NN+idx)*HD+col] : (float)v1h[(long)(b*NN+idx)*HD+col];
        }
    }
    s[col] = ssum;
    sv[col] = F32V1 ? v1f[(long)row*HD+col] : (float)v1h[(long)row*HD+col];
    __syncthreads();
    const float ic = 1.0f/(float)(cnt<1?1:cnt);
    float m = 0.f;
    for (int k=0;k<HD;++k) m += s[k]*W_msg[(long)k*HD+col];
    agg[col] = (m + 3.0f*b_msg[col])*ic;
    __syncthreads();
    float u = b_upd[col] + sv[col];
    for (int k=0;k<HD;++k) u += sv[k]*W_upd[(long)k*HD+col];
    for (int k=0;k<HD;++k) u += agg[k]*W_upd[(long)(HD+k)*HD+col];
    red[col] = u; __syncthreads();
    float mu=0.f;
    for (int k=0;k<HD;++k) mu += red[k];
    mu *= (1.f/HD);
    float var=0.f;
    for (int k=0;k<HD;++k){ const float d=red[k]-mu; var += d*d; }
    var *= (1.f/HD);
    vout[(long)row*HD+col] = (u-mu)*rsqrtf(var+1e-5f)*vng[col] + vnb[col];
}

// ---------- P3 (verified): residual MLP, in-place. One row per 256-thread block.
__global__ __launch_bounds__(256) void p_mlp(
    float* __restrict__ io, const float* __restrict__ W1, const float* __restrict__ b1,
    const float* __restrict__ W2, const float* __restrict__ b2)
{
    __shared__ float x[HD], h[2*HD];
    const int t = threadIdx.x;
    const long row = blockIdx.x;
    if (t < HD) x[t] = io[row*HD + t];
    __syncthreads();
    float a = b1[t];
    for (int k=0;k<HD;++k) a += x[k]*W1[(long)k*2*HD + t];
    h[t] = gelu_f(a);
    __syncthreads();
    if (t < HD){
        float y = x[t] + b2[t];
        for (int k=0;k<2*HD;++k) y += h[k]*W2[(long)k*HD + t];
        io[row*HD + t] = y;
    }
}

// ---------- P4 (verified): deflate + W_def + LN. One hex row per 128-thread block.
__global__ __launch_bounds__(128) void p_hex_a(
    const float* __restrict__ hexf, const float* __restrict__ vfin,
    const int* __restrict__ h2v,
    const float* __restrict__ W_def, const float* __restrict__ b_def,
    const float* __restrict__ hng, const float* __restrict__ hnb,
    float* __restrict__ hout)
{
    __shared__ float p[HD], red[HD];
    const int col = threadIdx.x;
    const int row = blockIdx.x;
    const int b = row / NT, t = row - b*NT;
    float ssum=0.f; int cnt=0;
    for (int j=0;j<6;++j){
        const int idx = h2v[t*6+j];
        if (idx>=0){ cnt++; ssum += vfin[(long)(b*NN+idx)*HD+col]; }
    }
    p[col] = ssum * (1.0f/(float)(cnt<1?1:cnt));
    __syncthreads();
    float u = b_def[col] + hexf[(long)row*HD+col];
    for (int k=0;k<HD;++k) u += p[k]*W_def[(long)k*HD+col];
    red[col]=u; __syncthreads();
    float mu=0.f;
    for (int k=0;k<HD;++k) mu += red[k];
    mu*=(1.f/HD);
    float var=0.f;
    for (int k=0;k<HD;++k){ const float d=red[k]-mu; var+=d*d; }
    var*=(1.f/HD);
    hout[(long)row*HD+col] = (u-mu)*rsqrtf(var+1e-5f)*hng[col] + hnb[col];
}

// ---------- TEST STAGE: MFMA residual MLP, in-place. 4 waves x 16 rows per block.
// per-wave LDS (f16): x[16][136]@0, h[16][264]@2176
__global__ __launch_bounds__(256) void k_mlp_mfma(
    float* __restrict__ io, const f16* __restrict__ BP1, const float* __restrict__ b1,
    const f16* __restrict__ BP2, const float* __restrict__ b2)
{
    __shared__ f16 lds[4*6400];
    const int tid=threadIdx.x, wave=tid>>6, lane=tid&63;
    const int l15=lane&15, kg=lane>>4;
    f16* Xl = lds + wave*6400;
    f16* Hl = Xl + 2176;
    const long tile0 = (long)(blockIdx.x*4+wave)*16;

    // stage x (f32 global -> f16 LDS), rows are wave-private
    for (int r=0;r<16;r++){
        f32x2 v = *(const f32x2*)(io + (tile0+r)*HD + lane*2);
        Xl[r*136 + lane*2]   = (f16)v[0];
        Xl[r*136 + lane*2+1] = (f16)v[1];
    }

    f32x4 acc[8];
    // h = gelu(x @ W1 + b1), 256 cols in 2 halves
#pragma unroll
    for (int half=0; half<2; half++){
#pragma unroll
        for (int i=0;i<8;i++) acc[i]=(f32x4){0.f,0.f,0.f,0.f};
#pragma unroll
        for (int kb=0;kb<4;kb++){
            f16x8 af = *(const f16x8*)(Xl + l15*136 + kb*32 + kg*8);
#pragma unroll
            for (int ct=0;ct<8;ct++){
                const int ctp = half*8+ct;
                f16x8 bf = *(const f16x8*)(BP1 + (((kb*16+ctp)*64+lane)<<3));
                acc[ct]=MFMA(af,bf,acc[ct]);
            }
        }
#pragma unroll
        for (int ct=0;ct<8;ct++){
            const int colg = half*128 + ct*16 + l15;
            const float bb = b1[colg];
#pragma unroll
            for (int r=0;r<4;r++){
                const int rl=kg*4+r;
                Hl[rl*264 + colg] = (f16)gelu_f(acc[ct][r]+bb);
            }
        }
    }

    // y = x(f32 re-read) + h @ W2 + b2
#pragma unroll
    for (int i=0;i<8;i++) acc[i]=(f32x4){0.f,0.f,0.f,0.f};
#pragma unroll
    for (int kb=0;kb<8;kb++){
        f16x8 af = *(const f16x8*)(Hl + l15*264 + kb*32 + kg*8);
#pragma unroll
        for (int ct=0;ct<8;ct++){
            f16x8 bf = *(const f16x8*)(BP2 + (((kb*8+ct)*64+lane)<<3));
            acc[ct]=MFMA(af,bf,acc[ct]);
        }
    }
#pragma unroll
    for (int ct=0;ct<8;ct++){
        const int col=ct*16+l15;
        const float bb=b2[col];
#pragma unroll
        for (int r=0;r<4;r++){
            const long row=tile0+kg*4+r;
            io[row*HD+col] = io[row*HD+col] + acc[ct][r] + bb;
        }
    }
}

extern "C" void kernel_launch(void* const* d_in, const int* in_sizes, int n_in,
                              void* d_out, int out_size, void* d_ws, size_t ws_size,
                              hipStream_t stream)
{
    (void)in_sizes; (void)n_in; (void)out_size;
    const float* hexf  = (const float*)d_in[0];
    const float* vertf = (const float*)d_in[1];
    const float* W_inf = (const float*)d_in[2];
    const float* b_inf = (const float*)d_in[3];
    const float* W_msg = (const float*)d_in[4];
    const float* b_msg = (const float*)d_in[5];
    const float* W_upd = (const float*)d_in[6];
    const float* b_upd = (const float*)d_in[7];
    const float* W_def = (const float*)d_in[8];
    const float* b_def = (const float*)d_in[9];
    const float* vng   = (const float*)d_in[10];
    const float* vnb   = (const float*)d_in[11];
    const float* hng   = (const float*)d_in[12];
    const float* hnb   = (const float*)d_in[13];
    const float* Wv1   = (const float*)d_in[14];
    const float* bv1   = (const float*)d_in[15];
    const float* Wv2   = (const float*)d_in[16];
    const float* bv2   = (const float*)d_in[17];
    const float* Wh1   = (const float*)d_in[18];
    const float* bh1   = (const float*)d_in[19];
    const float* Wh2   = (const float*)d_in[20];
    const float* bh2   = (const float*)d_in[21];
    const int* v2h   = (const int*)d_in[22];
    const int* h2v   = (const int*)d_in[23];
    const int* vadj  = (const int*)d_in[24];

    const long NV = (long)NB*NN;                 // 240000 vertex rows
    const size_t v1f_bytes = (size_t)NV*HD*4;    // 122.88 MB
    const size_t packs_bytes = (size_t)(128*256 + 256*128)*2;
    const bool f32v1 = (ws_size >= v1f_bytes + packs_bytes);

    float* v1f = (float*)d_ws;
    f16*   v1h = (f16*)d_ws;
    f16* packs = (f16*)((char*)d_ws + (f32v1 ? v1f_bytes : (size_t)NV*HD*2));
    f16* BPh1 = packs;                 // 128*256
    f16* BPh2 = BPh1 + 128*256;        // 256*128

    k_pack<<<(128*256)/256,256,0,stream>>>(Wh1, BPh1, 128,256);
    k_pack<<<(256*128)/256,256,0,stream>>>(Wh2, BPh2, 256,128);

    float* hout = (float*)d_out;
    float* vout = hout + (long)NB*NT*HD;

    if (f32v1){
        p_inflate<true><<<120000,256,0,stream>>>(hexf, vertf, v2h, W_inf, b_inf, v1f, v1h);
        p_vertex_a<true><<<240000,128,0,stream>>>(v1f, v1h, vadj, W_msg, b_msg, W_upd, b_upd,
                                                  vng, vnb, vout);
    } else {
        p_inflate<false><<<120000,256,0,stream>>>(hexf, vertf, v2h, W_inf, b_inf, v1f, v1h);
        p_vertex_a<false><<<240000,128,0,stream>>>(v1f, v1h, vadj, W_msg, b_msg, W_upd, b_upd,
                                                   vng, vnb, vout);
    }
    p_mlp<<<240000,256,0,stream>>>(vout, Wv1, bv1, Wv2, bv2);
    p_hex_a<<<80000,128,0,stream>>>(hexf, vout, h2v, W_def, b_def, hng, hnb, hout);
    k_mlp_mfma<<<1250,256,0,stream>>>(hout, BPh1, bh1, BPh2, bh2);
}

// Round 9
// 3804.573 us; speedup vs baseline: 1.8411x; 1.6948x over previous
//
#include <hip/hip_runtime.h>
#include <math.h>

typedef _Float16 f16;
typedef __attribute__((ext_vector_type(8))) _Float16 f16x8;
typedef __attribute__((ext_vector_type(4))) float f32x4;
typedef __attribute__((ext_vector_type(2))) float f32x2;

#define NB 4
#define NT 20000
#define NN 60000
#define HD 128

#define MFMA(a,b,c) __builtin_amdgcn_mfma_f32_16x16x32_f16((a),(b),(c),0,0,0)

__device__ __forceinline__ float gelu_f(float t){
    return 0.5f*t*(1.0f+erff(t*0.70710678118654752f));
}

// Pack weight W (K x Nc, row-major, f32) into f16 MFMA B-frag order:
// dst[((kb*NCT+ct)*64+lane)*8 + j] = f16(W[kb*32+(lane>>4)*8+j][ct*16+(lane&15)])
__global__ void k_pack(const float* __restrict__ src, f16* __restrict__ dst, int K, int Nc){
    int e = blockIdx.x*256 + threadIdx.x;
    if (e >= K*Nc) return;
    int j = e & 7;
    int lane = (e>>3) & 63;
    int tile = e >> 9;
    int nct = Nc >> 4;
    int ct = tile % nct;
    int kb = tile / nct;
    int k = kb*32 + ((lane>>4)<<3) + j;
    int n = ct*16 + (lane&15);
    dst[e] = (f16)src[k*Nc + n];
}

// ---------- P1 (verified): inflate. 2 rows per 256-thread block.
__global__ __launch_bounds__(256) void p_inflate(
    const float* __restrict__ hexf, const float* __restrict__ vertf,
    const int* __restrict__ v2h, const float* __restrict__ W_inf,
    const float* __restrict__ b_inf, float* __restrict__ v1f)
{
    const int col = threadIdx.x & 127;
    const int row = blockIdx.x*2 + (threadIdx.x>>7);
    const int b = row / NN, n = row - b*NN;
    float acc = b_inf[col];
    for (int slot=0; slot<3; ++slot){
        const int idx = v2h[n*3+slot];
        if (idx >= 0){
            const float* hp = hexf + (long)(b*NT+idx)*HD;
            const float* wp = W_inf + (long)(slot*HD)*HD + col;
            for (int k=0;k<HD;++k) acc += hp[k]*wp[(long)k*HD];
        }
    }
    const long a = (long)row*HD + col;
    v1f[a] = acc + vertf[a];
}

// ---------------- k_vertex2: MFMA vertex path, mapping-insensitive LN (v2)
// per-wave LDS (f16 idx): s/v1row@0 [16][136], agg@2176 [16][136],
//   u-f32 @byte 0 [16][132] (after MFMAs consumed s/agg), x@4352 [16][136], h@0 [16][264]
__global__ __launch_bounds__(256) void k_vertex2(
    const float* __restrict__ v1f, const int* __restrict__ vadj,
    const f16* __restrict__ BPmsg, const float* __restrict__ b_msg,
    const f16* __restrict__ BPupd, const float* __restrict__ b_upd,
    const float* __restrict__ vng, const float* __restrict__ vnb,
    const f16* __restrict__ BPv1, const float* __restrict__ bv1,
    const f16* __restrict__ BPv2, const float* __restrict__ bv2,
    float* __restrict__ vout)
{
    __shared__ f16 lds[4*6528];
    __shared__ float ics[4*16];
    const int tid=threadIdx.x, wave=tid>>6, lane=tid&63;
    const int l15=lane&15, kg=lane>>4;
    f16* Wl = lds + wave*6528;
    float* Wf = (float*)Wl;
    float* IC = ics + wave*16;
    const long tile0 = (long)(blockIdx.x*4+wave)*16;

    // s1: neighbor gather-sum -> s@0 (f16), inverse count
    for (int r=0;r<16;r++){
        const long row = tile0 + r;
        const int b = (int)(row / NN);
        const int n = (int)(row - (long)b*NN);
        float s0=0.f, s1=0.f; int cnt=0;
#pragma unroll
        for (int j=0;j<3;j++){
            const int idx = vadj[n*3+j];
            if (idx>=0){
                cnt++;
                f32x2 p = *(const f32x2*)(v1f + ((long)(b*NN+idx)*HD + lane*2));
                s0 += p[0]; s1 += p[1];
            }
        }
        Wl[r*136 + lane*2]   = (f16)s0;
        Wl[r*136 + lane*2+1] = (f16)s1;
        if (lane==0) IC[r] = 1.0f/(float)(cnt<1?1:cnt);
    }

    f32x4 acc[8];
    // s2: agg = (s @ W_msg + 3*b_msg)/cnt -> agg@2176 (f16)
#pragma unroll
    for (int i=0;i<8;i++) acc[i]=(f32x4){0.f,0.f,0.f,0.f};
#pragma unroll
    for (int kb=0;kb<4;kb++){
        f16x8 af = *(const f16x8*)(Wl + l15*136 + kb*32 + kg*8);
#pragma unroll
        for (int ct=0;ct<8;ct++){
            f16x8 bf = *(const f16x8*)(BPmsg + (((kb*8+ct)*64+lane)<<3));
            acc[ct]=MFMA(af,bf,acc[ct]);
        }
    }
#pragma unroll
    for (int ct=0;ct<8;ct++){
        const int col = ct*16+l15;
        const float bm = 3.0f*b_msg[col];
#pragma unroll
        for (int r=0;r<4;r++){
            const int rl = kg*4+r;
            Wl[2176 + rl*136 + col] = (f16)((acc[ct][r]+bm)*IC[rl]);
        }
    }

    // s3: restage v1 rows @0 (s is dead)
    for (int r=0;r<16;r++){
        f32x2 p = *(const f32x2*)(v1f + (tile0+r)*HD + lane*2);
        Wl[r*136 + lane*2]   = (f16)p[0];
        Wl[r*136 + lane*2+1] = (f16)p[1];
    }

    // s4: u_mat = [v1row, agg] @ W_upd
#pragma unroll
    for (int i=0;i<8;i++) acc[i]=(f32x4){0.f,0.f,0.f,0.f};
#pragma unroll
    for (int kb=0;kb<8;kb++){
        f16x8 af;
        if (kb<4) af = *(const f16x8*)(Wl + l15*136 + kb*32 + kg*8);
        else      af = *(const f16x8*)(Wl + 2176 + l15*136 + (kb-4)*32 + kg*8);
#pragma unroll
        for (int ct=0;ct<8;ct++){
            f16x8 bf = *(const f16x8*)(BPupd + (((kb*8+ct)*64+lane)<<3));
            acc[ct]=MFMA(af,bf,acc[ct]);
        }
    }
    // s5: scatter u (f32) @0 region, pitch 132 floats (v1row/agg dead)
#pragma unroll
    for (int ct=0;ct<8;ct++){
        const int col=ct*16+l15;
        const float bu = b_upd[col];
#pragma unroll
        for (int r=0;r<4;r++){
            const int rl=kg*4+r;
            const long row=tile0+rl;
            Wf[rl*132 + col] = acc[ct][r] + bu + v1f[row*HD+col];
        }
    }
    // s6: serial per-lane LN (lanes 0..15 own one row each) -> x@4352 (f16)
    if (lane < 16){
        const int rr = lane;
        float sum=0.f;
        for (int k=0;k<HD;++k) sum += Wf[rr*132+k];
        const float mu = sum*(1.f/HD);
        float sq=0.f;
        for (int k=0;k<HD;++k){ const float d=Wf[rr*132+k]-mu; sq += d*d; }
        const float rstd = rsqrtf(sq*(1.f/HD)+1e-5f);
        for (int k=0;k<HD;++k)
            Wl[4352 + rr*136 + k] = (f16)((Wf[rr*132+k]-mu)*rstd*vng[k]+vnb[k]);
    }

    // s7: h = gelu(x @ Wv1 + bv1) -> h@0 pitch 264 (u dead)
#pragma unroll
    for (int half=0; half<2; half++){
#pragma unroll
        for (int i=0;i<8;i++) acc[i]=(f32x4){0.f,0.f,0.f,0.f};
#pragma unroll
        for (int kb=0;kb<4;kb++){
            f16x8 af = *(const f16x8*)(Wl + 4352 + l15*136 + kb*32 + kg*8);
#pragma unroll
            for (int ct=0;ct<8;ct++){
                const int ctp = half*8+ct;
                f16x8 bf = *(const f16x8*)(BPv1 + (((kb*16+ctp)*64+lane)<<3));
                acc[ct]=MFMA(af,bf,acc[ct]);
            }
        }
#pragma unroll
        for (int ct=0;ct<8;ct++){
            const int colg = half*128 + ct*16 + l15;
            const float bb = bv1[colg];
#pragma unroll
            for (int r=0;r<4;r++){
                const int rl=kg*4+r;
                Wl[rl*264 + colg] = (f16)gelu_f(acc[ct][r]+bb);
            }
        }
    }

    // s8: y = x(LDS re-read) + h @ Wv2 + bv2 -> vout
#pragma unroll
    for (int i=0;i<8;i++) acc[i]=(f32x4){0.f,0.f,0.f,0.f};
#pragma unroll
    for (int kb=0;kb<8;kb++){
        f16x8 af = *(const f16x8*)(Wl + l15*264 + kb*32 + kg*8);
#pragma unroll
        for (int ct=0;ct<8;ct++){
            f16x8 bf = *(const f16x8*)(BPv2 + (((kb*8+ct)*64+lane)<<3));
            acc[ct]=MFMA(af,bf,acc[ct]);
        }
    }
#pragma unroll
    for (int ct=0;ct<8;ct++){
        const int col=ct*16+l15;
        const float bb=bv2[col];
#pragma unroll
        for (int r=0;r<4;r++){
            const int rl=kg*4+r;
            const long row=tile0+rl;
            vout[row*HD+col] = (float)Wl[4352+rl*136+col] + acc[ct][r] + bb;
        }
    }
}

// ---------------- k_hex2: MFMA hex path, mapping-insensitive LN (v2)
__global__ __launch_bounds__(256) void k_hex2(
    const float* __restrict__ hexf, const float* __restrict__ vfin,
    const int* __restrict__ h2v,
    const f16* __restrict__ BPdef, const float* __restrict__ b_def,
    const float* __restrict__ hng, const float* __restrict__ hnb,
    const f16* __restrict__ BPh1, const float* __restrict__ bh1,
    const f16* __restrict__ BPh2, const float* __restrict__ bh2,
    float* __restrict__ hout)
{
    __shared__ f16 lds[4*6528];
    const int tid=threadIdx.x, wave=tid>>6, lane=tid&63;
    const int l15=lane&15, kg=lane>>4;
    f16* Wl = lds + wave*6528;
    float* Wf = (float*)Wl;
    const long tile0 = (long)(blockIdx.x*4+wave)*16;

    // s1: pooled = masked-mean of 6 vertex rows -> p@0 (f16)
    for (int r=0;r<16;r++){
        const long row = tile0 + r;
        const int b = (int)(row / NT);
        const int t = (int)(row - (long)b*NT);
        float s0=0.f, s1=0.f; int cnt=0;
#pragma unroll
        for (int j=0;j<6;j++){
            const int idx = h2v[t*6+j];
            if (idx>=0){
                cnt++;
                f32x2 p = *(const f32x2*)(vfin + ((long)(b*NN+idx)*HD + lane*2));
                s0 += p[0]; s1 += p[1];
            }
        }
        const float ic = 1.0f/(float)(cnt<1?1:cnt);
        Wl[r*136 + lane*2]   = (f16)(s0*ic);
        Wl[r*136 + lane*2+1] = (f16)(s1*ic);
    }

    f32x4 acc[8];
    // s2: deflated = p @ W_def
#pragma unroll
    for (int i=0;i<8;i++) acc[i]=(f32x4){0.f,0.f,0.f,0.f};
#pragma unroll
    for (int kb=0;kb<4;kb++){
        f16x8 af = *(const f16x8*)(Wl + l15*136 + kb*32 + kg*8);
#pragma unroll
        for (int ct=0;ct<8;ct++){
            f16x8 bf = *(const f16x8*)(BPdef + (((kb*8+ct)*64+lane)<<3));
            acc[ct]=MFMA(af,bf,acc[ct]);
        }
    }
    // scatter u (f32) @0, pitch 132 (p dead)
#pragma unroll
    for (int ct=0;ct<8;ct++){
        const int col=ct*16+l15;
        const float bd = b_def[col];
#pragma unroll
        for (int r=0;r<4;r++){
            const int rl=kg*4+r;
            const long row=tile0+rl;
            Wf[rl*132 + col] = acc[ct][r] + bd + hexf[row*HD+col];
        }
    }
    // s3: serial per-lane LN -> x@4352
    if (lane < 16){
        const int rr = lane;
        float sum=0.f;
        for (int k=0;k<HD;++k) sum += Wf[rr*132+k];
        const float mu = sum*(1.f/HD);
        float sq=0.f;
        for (int k=0;k<HD;++k){ const float d=Wf[rr*132+k]-mu; sq += d*d; }
        const float rstd = rsqrtf(sq*(1.f/HD)+1e-5f);
        for (int k=0;k<HD;++k)
            Wl[4352 + rr*136 + k] = (f16)((Wf[rr*132+k]-mu)*rstd*hng[k]+hnb[k]);
    }

    // s4: h = gelu(x @ Wh1 + bh1) -> h@0 pitch 264
#pragma unroll
    for (int half=0; half<2; half++){
#pragma unroll
        for (int i=0;i<8;i++) acc[i]=(f32x4){0.f,0.f,0.f,0.f};
#pragma unroll
        for (int kb=0;kb<4;kb++){
            f16x8 af = *(const f16x8*)(Wl + 4352 + l15*136 + kb*32 + kg*8);
#pragma unroll
            for (int ct=0;ct<8;ct++){
                const int ctp = half*8+ct;
                f16x8 bf = *(const f16x8*)(BPh1 + (((kb*16+ctp)*64+lane)<<3));
                acc[ct]=MFMA(af,bf,acc[ct]);
            }
        }
#pragma unroll
        for (int ct=0;ct<8;ct++){
            const int colg = half*128 + ct*16 + l15;
            const float bb = bh1[colg];
#pragma unroll
            for (int r=0;r<4;r++){
                const int rl=kg*4+r;
                Wl[rl*264 + colg] = (f16)gelu_f(acc[ct][r]+bb);
            }
        }
    }

    // s5: out = x(LDS re-read) + h @ Wh2 + bh2 -> hout
#pragma unroll
    for (int i=0;i<8;i++) acc[i]=(f32x4){0.f,0.f,0.f,0.f};
#pragma unroll
    for (int kb=0;kb<8;kb++){
        f16x8 af = *(const f16x8*)(Wl + l15*264 + kb*32 + kg*8);
#pragma unroll
        for (int ct=0;ct<8;ct++){
            f16x8 bf = *(const f16x8*)(BPh2 + (((kb*8+ct)*64+lane)<<3));
            acc[ct]=MFMA(af,bf,acc[ct]);
        }
    }
#pragma unroll
    for (int ct=0;ct<8;ct++){
        const int col=ct*16+l15;
        const float bb=bh2[col];
#pragma unroll
        for (int r=0;r<4;r++){
            const int rl=kg*4+r;
            const long row=tile0+rl;
            hout[row*HD+col] = (float)Wl[4352+rl*136+col] + acc[ct][r] + bb;
        }
    }
}

extern "C" void kernel_launch(void* const* d_in, const int* in_sizes, int n_in,
                              void* d_out, int out_size, void* d_ws, size_t ws_size,
                              hipStream_t stream)
{
    (void)in_sizes; (void)n_in; (void)out_size; (void)ws_size;
    const float* hexf  = (const float*)d_in[0];
    const float* vertf = (const float*)d_in[1];
    const float* W_inf = (const float*)d_in[2];
    const float* b_inf = (const float*)d_in[3];
    const float* W_msg = (const float*)d_in[4];
    const float* b_msg = (const float*)d_in[5];
    const float* W_upd = (const float*)d_in[6];
    const float* b_upd = (const float*)d_in[7];
    const float* W_def = (const float*)d_in[8];
    const float* b_def = (const float*)d_in[9];
    const float* vng   = (const float*)d_in[10];
    const float* vnb   = (const float*)d_in[11];
    const float* hng   = (const float*)d_in[12];
    const float* hnb   = (const float*)d_in[13];
    const float* Wv1   = (const float*)d_in[14];
    const float* bv1   = (const float*)d_in[15];
    const float* Wv2   = (const float*)d_in[16];
    const float* bv2   = (const float*)d_in[17];
    const float* Wh1   = (const float*)d_in[18];
    const float* bh1   = (const float*)d_in[19];
    const float* Wh2   = (const float*)d_in[20];
    const float* bh2   = (const float*)d_in[21];
    const int* v2h   = (const int*)d_in[22];
    const int* h2v   = (const int*)d_in[23];
    const int* vadj  = (const int*)d_in[24];

    const long NV = (long)NB*NN;                 // 240000 vertex rows
    float* v1f = (float*)d_ws;                   // 122.88 MB (fits: confirmed by r5 WRITE_SIZE)
    f16* packs = (f16*)((char*)d_ws + (size_t)NV*HD*4);
    f16* BPmsg = packs;                // 128*128
    f16* BPupd = BPmsg + 128*128;      // 256*128
    f16* BPdef = BPupd + 256*128;      // 128*128
    f16* BPv1  = BPdef + 128*128;      // 128*256
    f16* BPv2  = BPv1 + 128*256;       // 256*128
    f16* BPh1  = BPv2 + 256*128;       // 128*256
    f16* BPh2  = BPh1 + 128*256;       // 256*128

    k_pack<<<(128*128)/256,256,0,stream>>>(W_msg, BPmsg, 128,128);
    k_pack<<<(256*128)/256,256,0,stream>>>(W_upd, BPupd, 256,128);
    k_pack<<<(128*128)/256,256,0,stream>>>(W_def, BPdef, 128,128);
    k_pack<<<(128*256)/256,256,0,stream>>>(Wv1,  BPv1, 128,256);
    k_pack<<<(256*128)/256,256,0,stream>>>(Wv2,  BPv2, 256,128);
    k_pack<<<(128*256)/256,256,0,stream>>>(Wh1,  BPh1, 128,256);
    k_pack<<<(256*128)/256,256,0,stream>>>(Wh2,  BPh2, 256,128);

    float* hout = (float*)d_out;
    float* vout = hout + (long)NB*NT*HD;

    p_inflate<<<120000,256,0,stream>>>(hexf, vertf, v2h, W_inf, b_inf, v1f);
    k_vertex2<<<3750,256,0,stream>>>(v1f, vadj, BPmsg, b_msg, BPupd, b_upd,
                                     vng, vnb, BPv1, bv1, BPv2, bv2, vout);
    k_hex2<<<1250,256,0,stream>>>(hexf, vout, h2v, BPdef, b_def, hng, hnb,
                                  BPh1, bh1, BPh2, bh2, hout);
}

// Round 10
// 1360.277 us; speedup vs baseline: 5.1494x; 2.7969x over previous
//
#include <hip/hip_runtime.h>
#include <math.h>

typedef _Float16 f16;
typedef __attribute__((ext_vector_type(8))) _Float16 f16x8;
typedef __attribute__((ext_vector_type(4))) float f32x4;
typedef __attribute__((ext_vector_type(2))) float f32x2;

#define NB 4
#define NT 20000
#define NN 60000
#define HD 128

#define MFMA(a,b,c) __builtin_amdgcn_mfma_f32_16x16x32_f16((a),(b),(c),0,0,0)

__device__ __forceinline__ float gelu_f(float t){
    return 0.5f*t*(1.0f+erff(t*0.70710678118654752f));
}

// Pack weight W (K x Nc, row-major, f32) into f16 MFMA B-frag order:
// dst[((kb*NCT+ct)*64+lane)*8 + j] = f16(W[kb*32+(lane>>4)*8+j][ct*16+(lane&15)])
__global__ void k_pack(const float* __restrict__ src, f16* __restrict__ dst, int K, int Nc){
    int e = blockIdx.x*256 + threadIdx.x;
    if (e >= K*Nc) return;
    int j = e & 7;
    int lane = (e>>3) & 63;
    int tile = e >> 9;
    int nct = Nc >> 4;
    int ct = tile % nct;
    int kb = tile / nct;
    int k = kb*32 + ((lane>>4)<<3) + j;
    int n = ct*16 + (lane&15);
    dst[e] = (f16)src[k*Nc + n];
}

// ---------------- k_inflate3: MFMA inflate (verified conventions from r9)
// A-frags gathered from global hexf (row = l15 of tile, masked), B packed, C/D epilogue
// pairs acc with externally-indexed vertf/v1f (pairing pattern HW-verified in r9 s5).
__global__ __launch_bounds__(256) void k_inflate3(
    const float* __restrict__ hexf, const float* __restrict__ vertf,
    const int* __restrict__ v2h, const f16* __restrict__ BPinf,
    const float* __restrict__ b_inf, float* __restrict__ v1f)
{
    const int tid = threadIdx.x;
    const int wave = tid>>6, lane = tid&63;
    const int l15 = lane&15, kg = lane>>4;
    const long tile0 = (long)(blockIdx.x*4 + wave)*16;
    const long ra = tile0 + l15;
    const int b = (int)(ra / NN);
    const int n = (int)(ra - (long)b*NN);
    const long hbase = (long)b*NT;
    int idx[3];
#pragma unroll
    for (int s=0;s<3;s++) idx[s] = v2h[n*3+s];

    f32x4 acc[8];
#pragma unroll
    for (int i=0;i<8;i++) acc[i]=(f32x4){0.f,0.f,0.f,0.f};

#pragma unroll
    for (int kb=0; kb<12; kb++){
        const int id = idx[kb>>2];
        f16x8 af = {0,0,0,0,0,0,0,0};
        if (id>=0){
            const float* p = hexf + ((hbase+id)*HD + (kb&3)*32 + kg*8);
            f32x4 x0 = *(const f32x4*)p;
            f32x4 x1 = *(const f32x4*)(p+4);
#pragma unroll
            for (int j=0;j<4;j++){ af[j]=(f16)x0[j]; af[4+j]=(f16)x1[j]; }
        }
#pragma unroll
        for (int ct=0; ct<8; ct++){
            f16x8 bf = *(const f16x8*)(BPinf + (((kb*8+ct)*64 + lane)<<3));
            acc[ct] = MFMA(af, bf, acc[ct]);
        }
    }
#pragma unroll
    for (int ct=0; ct<8; ct++){
        const int col = ct*16 + l15;
        const float bi = b_inf[col];
#pragma unroll
        for (int r=0;r<4;r++){
            const long row = tile0 + kg*4 + r;
            const long a = row*HD + col;
            v1f[a] = acc[ct][r] + bi + vertf[a];
        }
    }
}

// ---------------- k_vertex2: MFMA vertex path, mapping-insensitive LN (VERIFIED r9 — unchanged)
__global__ __launch_bounds__(256) void k_vertex2(
    const float* __restrict__ v1f, const int* __restrict__ vadj,
    const f16* __restrict__ BPmsg, const float* __restrict__ b_msg,
    const f16* __restrict__ BPupd, const float* __restrict__ b_upd,
    const float* __restrict__ vng, const float* __restrict__ vnb,
    const f16* __restrict__ BPv1, const float* __restrict__ bv1,
    const f16* __restrict__ BPv2, const float* __restrict__ bv2,
    float* __restrict__ vout)
{
    __shared__ f16 lds[4*6528];
    __shared__ float ics[4*16];
    const int tid=threadIdx.x, wave=tid>>6, lane=tid&63;
    const int l15=lane&15, kg=lane>>4;
    f16* Wl = lds + wave*6528;
    float* Wf = (float*)Wl;
    float* IC = ics + wave*16;
    const long tile0 = (long)(blockIdx.x*4+wave)*16;

    // s1: neighbor gather-sum -> s@0 (f16), inverse count
    for (int r=0;r<16;r++){
        const long row = tile0 + r;
        const int b = (int)(row / NN);
        const int n = (int)(row - (long)b*NN);
        float s0=0.f, s1=0.f; int cnt=0;
#pragma unroll
        for (int j=0;j<3;j++){
            const int idx = vadj[n*3+j];
            if (idx>=0){
                cnt++;
                f32x2 p = *(const f32x2*)(v1f + ((long)(b*NN+idx)*HD + lane*2));
                s0 += p[0]; s1 += p[1];
            }
        }
        Wl[r*136 + lane*2]   = (f16)s0;
        Wl[r*136 + lane*2+1] = (f16)s1;
        if (lane==0) IC[r] = 1.0f/(float)(cnt<1?1:cnt);
    }

    f32x4 acc[8];
    // s2: agg = (s @ W_msg + 3*b_msg)/cnt -> agg@2176 (f16)
#pragma unroll
    for (int i=0;i<8;i++) acc[i]=(f32x4){0.f,0.f,0.f,0.f};
#pragma unroll
    for (int kb=0;kb<4;kb++){
        f16x8 af = *(const f16x8*)(Wl + l15*136 + kb*32 + kg*8);
#pragma unroll
        for (int ct=0;ct<8;ct++){
            f16x8 bf = *(const f16x8*)(BPmsg + (((kb*8+ct)*64+lane)<<3));
            acc[ct]=MFMA(af,bf,acc[ct]);
        }
    }
#pragma unroll
    for (int ct=0;ct<8;ct++){
        const int col = ct*16+l15;
        const float bm = 3.0f*b_msg[col];
#pragma unroll
        for (int r=0;r<4;r++){
            const int rl = kg*4+r;
            Wl[2176 + rl*136 + col] = (f16)((acc[ct][r]+bm)*IC[rl]);
        }
    }

    // s3: restage v1 rows @0 (s is dead)
    for (int r=0;r<16;r++){
        f32x2 p = *(const f32x2*)(v1f + (tile0+r)*HD + lane*2);
        Wl[r*136 + lane*2]   = (f16)p[0];
        Wl[r*136 + lane*2+1] = (f16)p[1];
    }

    // s4: u_mat = [v1row, agg] @ W_upd
#pragma unroll
    for (int i=0;i<8;i++) acc[i]=(f32x4){0.f,0.f,0.f,0.f};
#pragma unroll
    for (int kb=0;kb<8;kb++){
        f16x8 af;
        if (kb<4) af = *(const f16x8*)(Wl + l15*136 + kb*32 + kg*8);
        else      af = *(const f16x8*)(Wl + 2176 + l15*136 + (kb-4)*32 + kg*8);
#pragma unroll
        for (int ct=0;ct<8;ct++){
            f16x8 bf = *(const f16x8*)(BPupd + (((kb*8+ct)*64+lane)<<3));
            acc[ct]=MFMA(af,bf,acc[ct]);
        }
    }
    // s5: scatter u (f32) @0 region, pitch 132 floats (v1row/agg dead)
#pragma unroll
    for (int ct=0;ct<8;ct++){
        const int col=ct*16+l15;
        const float bu = b_upd[col];
#pragma unroll
        for (int r=0;r<4;r++){
            const int rl=kg*4+r;
            const long row=tile0+rl;
            Wf[rl*132 + col] = acc[ct][r] + bu + v1f[row*HD+col];
        }
    }
    // s6: serial per-lane LN (lanes 0..15 own one row each) -> x@4352 (f16)
    if (lane < 16){
        const int rr = lane;
        float sum=0.f;
        for (int k=0;k<HD;++k) sum += Wf[rr*132+k];
        const float mu = sum*(1.f/HD);
        float sq=0.f;
        for (int k=0;k<HD;++k){ const float d=Wf[rr*132+k]-mu; sq += d*d; }
        const float rstd = rsqrtf(sq*(1.f/HD)+1e-5f);
        for (int k=0;k<HD;++k)
            Wl[4352 + rr*136 + k] = (f16)((Wf[rr*132+k]-mu)*rstd*vng[k]+vnb[k]);
    }

    // s7: h = gelu(x @ Wv1 + bv1) -> h@0 pitch 264 (u dead)
#pragma unroll
    for (int half=0; half<2; half++){
#pragma unroll
        for (int i=0;i<8;i++) acc[i]=(f32x4){0.f,0.f,0.f,0.f};
#pragma unroll
        for (int kb=0;kb<4;kb++){
            f16x8 af = *(const f16x8*)(Wl + 4352 + l15*136 + kb*32 + kg*8);
#pragma unroll
            for (int ct=0;ct<8;ct++){
                const int ctp = half*8+ct;
                f16x8 bf = *(const f16x8*)(BPv1 + (((kb*16+ctp)*64+lane)<<3));
                acc[ct]=MFMA(af,bf,acc[ct]);
            }
        }
#pragma unroll
        for (int ct=0;ct<8;ct++){
            const int colg = half*128 + ct*16 + l15;
            const float bb = bv1[colg];
#pragma unroll
            for (int r=0;r<4;r++){
                const int rl=kg*4+r;
                Wl[rl*264 + colg] = (f16)gelu_f(acc[ct][r]+bb);
            }
        }
    }

    // s8: y = x(LDS re-read) + h @ Wv2 + bv2 -> vout
#pragma unroll
    for (int i=0;i<8;i++) acc[i]=(f32x4){0.f,0.f,0.f,0.f};
#pragma unroll
    for (int kb=0;kb<8;kb++){
        f16x8 af = *(const f16x8*)(Wl + l15*264 + kb*32 + kg*8);
#pragma unroll
        for (int ct=0;ct<8;ct++){
            f16x8 bf = *(const f16x8*)(BPv2 + (((kb*8+ct)*64+lane)<<3));
            acc[ct]=MFMA(af,bf,acc[ct]);
        }
    }
#pragma unroll
    for (int ct=0;ct<8;ct++){
        const int col=ct*16+l15;
        const float bb=bv2[col];
#pragma unroll
        for (int r=0;r<4;r++){
            const int rl=kg*4+r;
            const long row=tile0+rl;
            vout[row*HD+col] = (float)Wl[4352+rl*136+col] + acc[ct][r] + bb;
        }
    }
}

// ---------------- k_hex2: MFMA hex path, mapping-insensitive LN (VERIFIED r9 — unchanged)
__global__ __launch_bounds__(256) void k_hex2(
    const float* __restrict__ hexf, const float* __restrict__ vfin,
    const int* __restrict__ h2v,
    const f16* __restrict__ BPdef, const float* __restrict__ b_def,
    const float* __restrict__ hng, const float* __restrict__ hnb,
    const f16* __restrict__ BPh1, const float* __restrict__ bh1,
    const f16* __restrict__ BPh2, const float* __restrict__ bh2,
    float* __restrict__ hout)
{
    __shared__ f16 lds[4*6528];
    const int tid=threadIdx.x, wave=tid>>6, lane=tid&63;
    const int l15=lane&15, kg=lane>>4;
    f16* Wl = lds + wave*6528;
    float* Wf = (float*)Wl;
    const long tile0 = (long)(blockIdx.x*4+wave)*16;

    // s1: pooled = masked-mean of 6 vertex rows -> p@0 (f16)
    for (int r=0;r<16;r++){
        const long row = tile0 + r;
        const int b = (int)(row / NT);
        const int t = (int)(row - (long)b*NT);
        float s0=0.f, s1=0.f; int cnt=0;
#pragma unroll
        for (int j=0;j<6;j++){
            const int idx = h2v[t*6+j];
            if (idx>=0){
                cnt++;
                f32x2 p = *(const f32x2*)(vfin + ((long)(b*NN+idx)*HD + lane*2));
                s0 += p[0]; s1 += p[1];
            }
        }
        const float ic = 1.0f/(float)(cnt<1?1:cnt);
        Wl[r*136 + lane*2]   = (f16)(s0*ic);
        Wl[r*136 + lane*2+1] = (f16)(s1*ic);
    }

    f32x4 acc[8];
    // s2: deflated = p @ W_def
#pragma unroll
    for (int i=0;i<8;i++) acc[i]=(f32x4){0.f,0.f,0.f,0.f};
#pragma unroll
    for (int kb=0;kb<4;kb++){
        f16x8 af = *(const f16x8*)(Wl + l15*136 + kb*32 + kg*8);
#pragma unroll
        for (int ct=0;ct<8;ct++){
            f16x8 bf = *(const f16x8*)(BPdef + (((kb*8+ct)*64+lane)<<3));
            acc[ct]=MFMA(af,bf,acc[ct]);
        }
    }
    // scatter u (f32) @0, pitch 132 (p dead)
#pragma unroll
    for (int ct=0;ct<8;ct++){
        const int col=ct*16+l15;
        const float bd = b_def[col];
#pragma unroll
        for (int r=0;r<4;r++){
            const int rl=kg*4+r;
            const long row=tile0+rl;
            Wf[rl*132 + col] = acc[ct][r] + bd + hexf[row*HD+col];
        }
    }
    // s3: serial per-lane LN -> x@4352
    if (lane < 16){
        const int rr = lane;
        float sum=0.f;
        for (int k=0;k<HD;++k) sum += Wf[rr*132+k];
        const float mu = sum*(1.f/HD);
        float sq=0.f;
        for (int k=0;k<HD;++k){ const float d=Wf[rr*132+k]-mu; sq += d*d; }
        const float rstd = rsqrtf(sq*(1.f/HD)+1e-5f);
        for (int k=0;k<HD;++k)
            Wl[4352 + rr*136 + k] = (f16)((Wf[rr*132+k]-mu)*rstd*hng[k]+hnb[k]);
    }

    // s4: h = gelu(x @ Wh1 + bh1) -> h@0 pitch 264
#pragma unroll
    for (int half=0; half<2; half++){
#pragma unroll
        for (int i=0;i<8;i++) acc[i]=(f32x4){0.f,0.f,0.f,0.f};
#pragma unroll
        for (int kb=0;kb<4;kb++){
            f16x8 af = *(const f16x8*)(Wl + 4352 + l15*136 + kb*32 + kg*8);
#pragma unroll
            for (int ct=0;ct<8;ct++){
                const int ctp = half*8+ct;
                f16x8 bf = *(const f16x8*)(BPh1 + (((kb*16+ctp)*64+lane)<<3));
                acc[ct]=MFMA(af,bf,acc[ct]);
            }
        }
#pragma unroll
        for (int ct=0;ct<8;ct++){
            const int colg = half*128 + ct*16 + l15;
            const float bb = bh1[colg];
#pragma unroll
            for (int r=0;r<4;r++){
                const int rl=kg*4+r;
                Wl[rl*264 + colg] = (f16)gelu_f(acc[ct][r]+bb);
            }
        }
    }

    // s5: out = x(LDS re-read) + h @ Wh2 + bh2 -> hout
#pragma unroll
    for (int i=0;i<8;i++) acc[i]=(f32x4){0.f,0.f,0.f,0.f};
#pragma unroll
    for (int kb=0;kb<8;kb++){
        f16x8 af = *(const f16x8*)(Wl + l15*264 + kb*32 + kg*8);
#pragma unroll
        for (int ct=0;ct<8;ct++){
            f16x8 bf = *(const f16x8*)(BPh2 + (((kb*8+ct)*64+lane)<<3));
            acc[ct]=MFMA(af,bf,acc[ct]);
        }
    }
#pragma unroll
    for (int ct=0;ct<8;ct++){
        const int col=ct*16+l15;
        const float bb=bh2[col];
#pragma unroll
        for (int r=0;r<4;r++){
            const int rl=kg*4+r;
            const long row=tile0+rl;
            hout[row*HD+col] = (float)Wl[4352+rl*136+col] + acc[ct][r] + bb;
        }
    }
}

extern "C" void kernel_launch(void* const* d_in, const int* in_sizes, int n_in,
                              void* d_out, int out_size, void* d_ws, size_t ws_size,
                              hipStream_t stream)
{
    (void)in_sizes; (void)n_in; (void)out_size; (void)ws_size;
    const float* hexf  = (const float*)d_in[0];
    const float* vertf = (const float*)d_in[1];
    const float* W_inf = (const float*)d_in[2];
    const float* b_inf = (const float*)d_in[3];
    const float* W_msg = (const float*)d_in[4];
    const float* b_msg = (const float*)d_in[5];
    const float* W_upd = (const float*)d_in[6];
    const float* b_upd = (const float*)d_in[7];
    const float* W_def = (const float*)d_in[8];
    const float* b_def = (const float*)d_in[9];
    const float* vng   = (const float*)d_in[10];
    const float* vnb   = (const float*)d_in[11];
    const float* hng   = (const float*)d_in[12];
    const float* hnb   = (const float*)d_in[13];
    const float* Wv1   = (const float*)d_in[14];
    const float* bv1   = (const float*)d_in[15];
    const float* Wv2   = (const float*)d_in[16];
    const float* bv2   = (const float*)d_in[17];
    const float* Wh1   = (const float*)d_in[18];
    const float* bh1   = (const float*)d_in[19];
    const float* Wh2   = (const float*)d_in[20];
    const float* bh2   = (const float*)d_in[21];
    const int* v2h   = (const int*)d_in[22];
    const int* h2v   = (const int*)d_in[23];
    const int* vadj  = (const int*)d_in[24];

    const long NV = (long)NB*NN;                 // 240000 vertex rows
    float* v1f = (float*)d_ws;                   // 122.88 MB
    f16* packs = (f16*)((char*)d_ws + (size_t)NV*HD*4);
    f16* BPinf = packs;                // 384*128
    f16* BPmsg = BPinf + 384*128;      // 128*128
    f16* BPupd = BPmsg + 128*128;      // 256*128
    f16* BPdef = BPupd + 256*128;      // 128*128
    f16* BPv1  = BPdef + 128*128;      // 128*256
    f16* BPv2  = BPv1 + 128*256;       // 256*128
    f16* BPh1  = BPv2 + 256*128;       // 128*256
    f16* BPh2  = BPh1 + 128*256;       // 256*128

    k_pack<<<(384*128)/256,256,0,stream>>>(W_inf, BPinf, 384,128);
    k_pack<<<(128*128)/256,256,0,stream>>>(W_msg, BPmsg, 128,128);
    k_pack<<<(256*128)/256,256,0,stream>>>(W_upd, BPupd, 256,128);
    k_pack<<<(128*128)/256,256,0,stream>>>(W_def, BPdef, 128,128);
    k_pack<<<(128*256)/256,256,0,stream>>>(Wv1,  BPv1, 128,256);
    k_pack<<<(256*128)/256,256,0,stream>>>(Wv2,  BPv2, 256,128);
    k_pack<<<(128*256)/256,256,0,stream>>>(Wh1,  BPh1, 128,256);
    k_pack<<<(256*128)/256,256,0,stream>>>(Wh2,  BPh2, 256,128);

    float* hout = (float*)d_out;
    float* vout = hout + (long)NB*NT*HD;

    k_inflate3<<<3750,256,0,stream>>>(hexf, vertf, v2h, BPinf, b_inf, v1f);
    k_vertex2<<<3750,256,0,stream>>>(v1f, vadj, BPmsg, b_msg, BPupd, b_upd,
                                     vng, vnb, BPv1, bv1, BPv2, bv2, vout);
    k_hex2<<<1250,256,0,stream>>>(hexf, vout, h2v, BPdef, b_def, hng, hnb,
                                  BPh1, bh1, BPh2, bh2, hout);
}

// Round 11
// 748.819 us; speedup vs baseline: 9.3541x; 1.8166x over previous
//
#include <hip/hip_runtime.h>
#include <math.h>

typedef _Float16 f16;
typedef __attribute__((ext_vector_type(8))) _Float16 f16x8;
typedef __attribute__((ext_vector_type(4))) _Float16 f16x4;
typedef __attribute__((ext_vector_type(4))) float f32x4;
typedef __attribute__((ext_vector_type(2))) float f32x2;

#define NB 4
#define NT 20000
#define NN 60000
#define HD 128

#define MFMA(a,b,c) __builtin_amdgcn_mfma_f32_16x16x32_f16((a),(b),(c),0,0,0)

__device__ __forceinline__ float gelu_f(float t){
    return 0.5f*t*(1.0f+erff(t*0.70710678118654752f));
}

// Pack weight W (K x Nc, row-major, f32) into f16 MFMA B-frag order:
// dst[((kb*NCT+ct)*64+lane)*8 + j] = f16(W[kb*32+(lane>>4)*8+j][ct*16+(lane&15)])
__global__ void k_pack(const float* __restrict__ src, f16* __restrict__ dst, int K, int Nc){
    int e = blockIdx.x*256 + threadIdx.x;
    if (e >= K*Nc) return;
    int j = e & 7;
    int lane = (e>>3) & 63;
    int tile = e >> 9;
    int nct = Nc >> 4;
    int ct = tile % nct;
    int kb = tile / nct;
    int k = kb*32 + ((lane>>4)<<3) + j;
    int n = ct*16 + (lane&15);
    dst[e] = (f16)src[k*Nc + n];
}

// ---------------- k_inflate3: MFMA inflate (VERIFIED r10 — unchanged)
__global__ __launch_bounds__(256) void k_inflate3(
    const float* __restrict__ hexf, const float* __restrict__ vertf,
    const int* __restrict__ v2h, const f16* __restrict__ BPinf,
    const float* __restrict__ b_inf, float* __restrict__ v1f)
{
    const int tid = threadIdx.x;
    const int wave = tid>>6, lane = tid&63;
    const int l15 = lane&15, kg = lane>>4;
    const long tile0 = (long)(blockIdx.x*4 + wave)*16;
    const long ra = tile0 + l15;
    const int b = (int)(ra / NN);
    const int n = (int)(ra - (long)b*NN);
    const long hbase = (long)b*NT;
    int idx[3];
#pragma unroll
    for (int s=0;s<3;s++) idx[s] = v2h[n*3+s];

    f32x4 acc[8];
#pragma unroll
    for (int i=0;i<8;i++) acc[i]=(f32x4){0.f,0.f,0.f,0.f};

#pragma unroll
    for (int kb=0; kb<12; kb++){
        const int id = idx[kb>>2];
        f16x8 af = {0,0,0,0,0,0,0,0};
        if (id>=0){
            const float* p = hexf + ((hbase+id)*HD + (kb&3)*32 + kg*8);
            f32x4 x0 = *(const f32x4*)p;
            f32x4 x1 = *(const f32x4*)(p+4);
#pragma unroll
            for (int j=0;j<4;j++){ af[j]=(f16)x0[j]; af[4+j]=(f16)x1[j]; }
        }
#pragma unroll
        for (int ct=0; ct<8; ct++){
            f16x8 bf = *(const f16x8*)(BPinf + (((kb*8+ct)*64 + lane)<<3));
            acc[ct] = MFMA(af, bf, acc[ct]);
        }
    }
#pragma unroll
    for (int ct=0; ct<8; ct++){
        const int col = ct*16 + l15;
        const float bi = b_inf[col];
#pragma unroll
        for (int r=0;r<4;r++){
            const long row = tile0 + kg*4 + r;
            const long a = row*HD + col;
            v1f[a] = acc[ct][r] + bi + vertf[a];
        }
    }
}

// ---------------- k_vertex2: MFMA vertex path (structure VERIFIED r9/r10;
// this round: parallel 64-lane LN from the verified u-scatter + unrolled gathers)
__global__ __launch_bounds__(256) void k_vertex2(
    const float* __restrict__ v1f, const int* __restrict__ vadj,
    const f16* __restrict__ BPmsg, const float* __restrict__ b_msg,
    const f16* __restrict__ BPupd, const float* __restrict__ b_upd,
    const float* __restrict__ vng, const float* __restrict__ vnb,
    const f16* __restrict__ BPv1, const float* __restrict__ bv1,
    const f16* __restrict__ BPv2, const float* __restrict__ bv2,
    float* __restrict__ vout)
{
    __shared__ f16 lds[4*6528];
    __shared__ float ics[4*16];
    __shared__ float pscr[4*64];
    const int tid=threadIdx.x, wave=tid>>6, lane=tid&63;
    const int l15=lane&15, kg=lane>>4;
    f16* Wl = lds + wave*6528;
    float* Wf = (float*)Wl;          // u region, pitch 133 floats (spans f16 [0,4256) < 4352)
    float* IC = ics + wave*16;
    float* Pf = pscr + wave*64;
    const long tile0 = (long)(blockIdx.x*4+wave)*16;

    // s1: neighbor gather-sum -> s@0 (f16), inverse count  [unrolled for load pipelining]
#pragma unroll 4
    for (int r=0;r<16;r++){
        const long row = tile0 + r;
        const int b = (int)(row / NN);
        const int n = (int)(row - (long)b*NN);
        float s0=0.f, s1=0.f; int cnt=0;
#pragma unroll
        for (int j=0;j<3;j++){
            const int idx = vadj[n*3+j];
            if (idx>=0){
                cnt++;
                f32x2 p = *(const f32x2*)(v1f + ((long)(b*NN+idx)*HD + lane*2));
                s0 += p[0]; s1 += p[1];
            }
        }
        Wl[r*136 + lane*2]   = (f16)s0;
        Wl[r*136 + lane*2+1] = (f16)s1;
        if (lane==0) IC[r] = 1.0f/(float)(cnt<1?1:cnt);
    }

    f32x4 acc[8];
    // s2: agg = (s @ W_msg + 3*b_msg)/cnt -> agg@2176 (f16)
#pragma unroll
    for (int i=0;i<8;i++) acc[i]=(f32x4){0.f,0.f,0.f,0.f};
#pragma unroll
    for (int kb=0;kb<4;kb++){
        f16x8 af = *(const f16x8*)(Wl + l15*136 + kb*32 + kg*8);
#pragma unroll
        for (int ct=0;ct<8;ct++){
            f16x8 bf = *(const f16x8*)(BPmsg + (((kb*8+ct)*64+lane)<<3));
            acc[ct]=MFMA(af,bf,acc[ct]);
        }
    }
#pragma unroll
    for (int ct=0;ct<8;ct++){
        const int col = ct*16+l15;
        const float bm = 3.0f*b_msg[col];
#pragma unroll
        for (int r=0;r<4;r++){
            const int rl = kg*4+r;
            Wl[2176 + rl*136 + col] = (f16)((acc[ct][r]+bm)*IC[rl]);
        }
    }

    // s3: restage v1 rows @0 (s is dead)  [unrolled]
#pragma unroll
    for (int r=0;r<16;r++){
        f32x2 p = *(const f32x2*)(v1f + (tile0+r)*HD + lane*2);
        Wl[r*136 + lane*2]   = (f16)p[0];
        Wl[r*136 + lane*2+1] = (f16)p[1];
    }

    // s4: u_mat = [v1row, agg] @ W_upd
#pragma unroll
    for (int i=0;i<8;i++) acc[i]=(f32x4){0.f,0.f,0.f,0.f};
#pragma unroll
    for (int kb=0;kb<8;kb++){
        f16x8 af;
        if (kb<4) af = *(const f16x8*)(Wl + l15*136 + kb*32 + kg*8);
        else      af = *(const f16x8*)(Wl + 2176 + l15*136 + (kb-4)*32 + kg*8);
#pragma unroll
        for (int ct=0;ct<8;ct++){
            f16x8 bf = *(const f16x8*)(BPupd + (((kb*8+ct)*64+lane)<<3));
            acc[ct]=MFMA(af,bf,acc[ct]);
        }
    }
    // s5: scatter u (f32) @0, pitch 133 (v1row/agg dead) — verified pairing
#pragma unroll
    for (int ct=0;ct<8;ct++){
        const int col=ct*16+l15;
        const float bu = b_upd[col];
#pragma unroll
        for (int r=0;r<4;r++){
            const int rl=kg*4+r;
            const long row=tile0+rl;
            Wf[rl*133 + col] = acc[ct][r] + bu + v1f[row*HD+col];
        }
    }
    // s6: parallel LN — 4 lanes per row, reads verified u rows from LDS -> x@4352 (f16)
    {
        const int rr = lane>>2, q = lane&3;
        const float* Rf = Wf + rr*133 + q*32;
        f32x4 vv[8];
        float ps=0.f;
#pragma unroll
        for (int i=0;i<8;i++){
            vv[i] = *(const f32x4*)(Rf + i*4);
            ps += (vv[i][0]+vv[i][1])+(vv[i][2]+vv[i][3]);
        }
        Pf[lane]=ps;
        const float sum = Pf[rr*4]+Pf[rr*4+1]+Pf[rr*4+2]+Pf[rr*4+3];
        const float mu = sum*(1.f/HD);
        float pq=0.f;
#pragma unroll
        for (int i=0;i<8;i++){
#pragma unroll
            for (int j=0;j<4;j++){ const float d=vv[i][j]-mu; pq += d*d; }
        }
        Pf[lane]=pq;
        const float sq = Pf[rr*4]+Pf[rr*4+1]+Pf[rr*4+2]+Pf[rr*4+3];
        const float rstd = rsqrtf(sq*(1.f/HD)+1e-5f);
#pragma unroll
        for (int i=0;i<8;i++){
            f32x4 g4 = *(const f32x4*)(vng + q*32 + i*4);
            f32x4 b4 = *(const f32x4*)(vnb + q*32 + i*4);
            f16x4 o;
#pragma unroll
            for (int j=0;j<4;j++) o[j] = (f16)((vv[i][j]-mu)*rstd*g4[j]+b4[j]);
            *(f16x4*)(Wl + 4352 + rr*136 + q*32 + i*4) = o;
        }
    }

    // s7: h = gelu(x @ Wv1 + bv1) -> h@0 pitch 264 (u dead)
#pragma unroll
    for (int half=0; half<2; half++){
#pragma unroll
        for (int i=0;i<8;i++) acc[i]=(f32x4){0.f,0.f,0.f,0.f};
#pragma unroll
        for (int kb=0;kb<4;kb++){
            f16x8 af = *(const f16x8*)(Wl + 4352 + l15*136 + kb*32 + kg*8);
#pragma unroll
            for (int ct=0;ct<8;ct++){
                const int ctp = half*8+ct;
                f16x8 bf = *(const f16x8*)(BPv1 + (((kb*16+ctp)*64+lane)<<3));
                acc[ct]=MFMA(af,bf,acc[ct]);
            }
        }
#pragma unroll
        for (int ct=0;ct<8;ct++){
            const int colg = half*128 + ct*16 + l15;
            const float bb = bv1[colg];
#pragma unroll
            for (int r=0;r<4;r++){
                const int rl=kg*4+r;
                Wl[rl*264 + colg] = (f16)gelu_f(acc[ct][r]+bb);
            }
        }
    }

    // s8: y = x(LDS re-read) + h @ Wv2 + bv2 -> vout
#pragma unroll
    for (int i=0;i<8;i++) acc[i]=(f32x4){0.f,0.f,0.f,0.f};
#pragma unroll
    for (int kb=0;kb<8;kb++){
        f16x8 af = *(const f16x8*)(Wl + l15*264 + kb*32 + kg*8);
#pragma unroll
        for (int ct=0;ct<8;ct++){
            f16x8 bf = *(const f16x8*)(BPv2 + (((kb*8+ct)*64+lane)<<3));
            acc[ct]=MFMA(af,bf,acc[ct]);
        }
    }
#pragma unroll
    for (int ct=0;ct<8;ct++){
        const int col=ct*16+l15;
        const float bb=bv2[col];
#pragma unroll
        for (int r=0;r<4;r++){
            const int rl=kg*4+r;
            const long row=tile0+rl;
            vout[row*HD+col] = (float)Wl[4352+rl*136+col] + acc[ct][r] + bb;
        }
    }
}

// ---------------- k_hex2: MFMA hex path (same upgrades)
__global__ __launch_bounds__(256) void k_hex2(
    const float* __restrict__ hexf, const float* __restrict__ vfin,
    const int* __restrict__ h2v,
    const f16* __restrict__ BPdef, const float* __restrict__ b_def,
    const float* __restrict__ hng, const float* __restrict__ hnb,
    const f16* __restrict__ BPh1, const float* __restrict__ bh1,
    const f16* __restrict__ BPh2, const float* __restrict__ bh2,
    float* __restrict__ hout)
{
    __shared__ f16 lds[4*6528];
    __shared__ float pscr[4*64];
    const int tid=threadIdx.x, wave=tid>>6, lane=tid&63;
    const int l15=lane&15, kg=lane>>4;
    f16* Wl = lds + wave*6528;
    float* Wf = (float*)Wl;
    float* Pf = pscr + wave*64;
    const long tile0 = (long)(blockIdx.x*4+wave)*16;

    // s1: pooled = masked-mean of 6 vertex rows -> p@0 (f16)  [unrolled]
#pragma unroll 2
    for (int r=0;r<16;r++){
        const long row = tile0 + r;
        const int b = (int)(row / NT);
        const int t = (int)(row - (long)b*NT);
        float s0=0.f, s1=0.f; int cnt=0;
#pragma unroll
        for (int j=0;j<6;j++){
            const int idx = h2v[t*6+j];
            if (idx>=0){
                cnt++;
                f32x2 p = *(const f32x2*)(vfin + ((long)(b*NN+idx)*HD + lane*2));
                s0 += p[0]; s1 += p[1];
            }
        }
        const float ic = 1.0f/(float)(cnt<1?1:cnt);
        Wl[r*136 + lane*2]   = (f16)(s0*ic);
        Wl[r*136 + lane*2+1] = (f16)(s1*ic);
    }

    f32x4 acc[8];
    // s2: deflated = p @ W_def
#pragma unroll
    for (int i=0;i<8;i++) acc[i]=(f32x4){0.f,0.f,0.f,0.f};
#pragma unroll
    for (int kb=0;kb<4;kb++){
        f16x8 af = *(const f16x8*)(Wl + l15*136 + kb*32 + kg*8);
#pragma unroll
        for (int ct=0;ct<8;ct++){
            f16x8 bf = *(const f16x8*)(BPdef + (((kb*8+ct)*64+lane)<<3));
            acc[ct]=MFMA(af,bf,acc[ct]);
        }
    }
    // scatter u (f32) @0, pitch 133 (p dead)
#pragma unroll
    for (int ct=0;ct<8;ct++){
        const int col=ct*16+l15;
        const float bd = b_def[col];
#pragma unroll
        for (int r=0;r<4;r++){
            const int rl=kg*4+r;
            const long row=tile0+rl;
            Wf[rl*133 + col] = acc[ct][r] + bd + hexf[row*HD+col];
        }
    }
    // s3: parallel LN -> x@4352
    {
        const int rr = lane>>2, q = lane&3;
        const float* Rf = Wf + rr*133 + q*32;
        f32x4 vv[8];
        float ps=0.f;
#pragma unroll
        for (int i=0;i<8;i++){
            vv[i] = *(const f32x4*)(Rf + i*4);
            ps += (vv[i][0]+vv[i][1])+(vv[i][2]+vv[i][3]);
        }
        Pf[lane]=ps;
        const float sum = Pf[rr*4]+Pf[rr*4+1]+Pf[rr*4+2]+Pf[rr*4+3];
        const float mu = sum*(1.f/HD);
        float pq=0.f;
#pragma unroll
        for (int i=0;i<8;i++){
#pragma unroll
            for (int j=0;j<4;j++){ const float d=vv[i][j]-mu; pq += d*d; }
        }
        Pf[lane]=pq;
        const float sq = Pf[rr*4]+Pf[rr*4+1]+Pf[rr*4+2]+Pf[rr*4+3];
        const float rstd = rsqrtf(sq*(1.f/HD)+1e-5f);
#pragma unroll
        for (int i=0;i<8;i++){
            f32x4 g4 = *(const f32x4*)(hng + q*32 + i*4);
            f32x4 b4 = *(const f32x4*)(hnb + q*32 + i*4);
            f16x4 o;
#pragma unroll
            for (int j=0;j<4;j++) o[j] = (f16)((vv[i][j]-mu)*rstd*g4[j]+b4[j]);
            *(f16x4*)(Wl + 4352 + rr*136 + q*32 + i*4) = o;
        }
    }

    // s4: h = gelu(x @ Wh1 + bh1) -> h@0 pitch 264
#pragma unroll
    for (int half=0; half<2; half++){
#pragma unroll
        for (int i=0;i<8;i++) acc[i]=(f32x4){0.f,0.f,0.f,0.f};
#pragma unroll
        for (int kb=0;kb<4;kb++){
            f16x8 af = *(const f16x8*)(Wl + 4352 + l15*136 + kb*32 + kg*8);
#pragma unroll
            for (int ct=0;ct<8;ct++){
                const int ctp = half*8+ct;
                f16x8 bf = *(const f16x8*)(BPh1 + (((kb*16+ctp)*64+lane)<<3));
                acc[ct]=MFMA(af,bf,acc[ct]);
            }
        }
#pragma unroll
        for (int ct=0;ct<8;ct++){
            const int colg = half*128 + ct*16 + l15;
            const float bb = bh1[colg];
#pragma unroll
            for (int r=0;r<4;r++){
                const int rl=kg*4+r;
                Wl[rl*264 + colg] = (f16)gelu_f(acc[ct][r]+bb);
            }
        }
    }

    // s5: out = x(LDS re-read) + h @ Wh2 + bh2 -> hout
#pragma unroll
    for (int i=0;i<8;i++) acc[i]=(f32x4){0.f,0.f,0.f,0.f};
#pragma unroll
    for (int kb=0;kb<8;kb++){
        f16x8 af = *(const f16x8*)(Wl + l15*264 + kb*32 + kg*8);
#pragma unroll
        for (int ct=0;ct<8;ct++){
            f16x8 bf = *(const f16x8*)(BPh2 + (((kb*8+ct)*64+lane)<<3));
            acc[ct]=MFMA(af,bf,acc[ct]);
        }
    }
#pragma unroll
    for (int ct=0;ct<8;ct++){
        const int col=ct*16+l15;
        const float bb=bh2[col];
#pragma unroll
        for (int r=0;r<4;r++){
            const int rl=kg*4+r;
            const long row=tile0+rl;
            hout[row*HD+col] = (float)Wl[4352+rl*136+col] + acc[ct][r] + bb;
        }
    }
}

extern "C" void kernel_launch(void* const* d_in, const int* in_sizes, int n_in,
                              void* d_out, int out_size, void* d_ws, size_t ws_size,
                              hipStream_t stream)
{
    (void)in_sizes; (void)n_in; (void)out_size; (void)ws_size;
    const float* hexf  = (const float*)d_in[0];
    const float* vertf = (const float*)d_in[1];
    const float* W_inf = (const float*)d_in[2];
    const float* b_inf = (const float*)d_in[3];
    const float* W_msg = (const float*)d_in[4];
    const float* b_msg = (const float*)d_in[5];
    const float* W_upd = (const float*)d_in[6];
    const float* b_upd = (const float*)d_in[7];
    const float* W_def = (const float*)d_in[8];
    const float* b_def = (const float*)d_in[9];
    const float* vng   = (const float*)d_in[10];
    const float* vnb   = (const float*)d_in[11];
    const float* hng   = (const float*)d_in[12];
    const float* hnb   = (const float*)d_in[13];
    const float* Wv1   = (const float*)d_in[14];
    const float* bv1   = (const float*)d_in[15];
    const float* Wv2   = (const float*)d_in[16];
    const float* bv2   = (const float*)d_in[17];
    const float* Wh1   = (const float*)d_in[18];
    const float* bh1   = (const float*)d_in[19];
    const float* Wh2   = (const float*)d_in[20];
    const float* bh2   = (const float*)d_in[21];
    const int* v2h   = (const int*)d_in[22];
    const int* h2v   = (const int*)d_in[23];
    const int* vadj  = (const int*)d_in[24];

    const long NV = (long)NB*NN;                 // 240000 vertex rows
    float* v1f = (float*)d_ws;                   // 122.88 MB
    f16* packs = (f16*)((char*)d_ws + (size_t)NV*HD*4);
    f16* BPinf = packs;                // 384*128
    f16* BPmsg = BPinf + 384*128;      // 128*128
    f16* BPupd = BPmsg + 128*128;      // 256*128
    f16* BPdef = BPupd + 256*128;      // 128*128
    f16* BPv1  = BPdef + 128*128;      // 128*256
    f16* BPv2  = BPv1 + 128*256;       // 256*128
    f16* BPh1  = BPv2 + 256*128;       // 128*256
    f16* BPh2  = BPh1 + 128*256;       // 256*128

    k_pack<<<(384*128)/256,256,0,stream>>>(W_inf, BPinf, 384,128);
    k_pack<<<(128*128)/256,256,0,stream>>>(W_msg, BPmsg, 128,128);
    k_pack<<<(256*128)/256,256,0,stream>>>(W_upd, BPupd, 256,128);
    k_pack<<<(128*128)/256,256,0,stream>>>(W_def, BPdef, 128,128);
    k_pack<<<(128*256)/256,256,0,stream>>>(Wv1,  BPv1, 128,256);
    k_pack<<<(256*128)/256,256,0,stream>>>(Wv2,  BPv2, 256,128);
    k_pack<<<(128*256)/256,256,0,stream>>>(Wh1,  BPh1, 128,256);
    k_pack<<<(256*128)/256,256,0,stream>>>(Wh2,  BPh2, 256,128);

    float* hout = (float*)d_out;
    float* vout = hout + (long)NB*NT*HD;

    k_inflate3<<<3750,256,0,stream>>>(hexf, vertf, v2h, BPinf, b_inf, v1f);
    k_vertex2<<<3750,256,0,stream>>>(v1f, vadj, BPmsg, b_msg, BPupd, b_upd,
                                     vng, vnb, BPv1, bv1, BPv2, bv2, vout);
    k_hex2<<<1250,256,0,stream>>>(hexf, vout, h2v, BPdef, b_def, hng, hnb,
                                  BPh1, bh1, BPh2, bh2, hout);
}

// Round 12
// 704.600 us; speedup vs baseline: 9.9412x; 1.0628x over previous
//
#include <hip/hip_runtime.h>
#include <math.h>

typedef _Float16 f16;
typedef __attribute__((ext_vector_type(8))) _Float16 f16x8;
typedef __attribute__((ext_vector_type(4))) _Float16 f16x4;
typedef __attribute__((ext_vector_type(4))) float f32x4;
typedef __attribute__((ext_vector_type(2))) float f32x2;

#define NB 4
#define NT 20000
#define NN 60000
#define HD 128

#define MFMA(a,b,c) __builtin_amdgcn_mfma_f32_16x16x32_f16((a),(b),(c),0,0,0)

__device__ __forceinline__ float gelu_f(float t){
    return 0.5f*t*(1.0f+erff(t*0.70710678118654752f));
}

// Pack weight W (K x Nc, row-major, f32) into f16 MFMA B-frag order:
// dst[((kb*NCT+ct)*64+lane)*8 + j] = f16(W[kb*32+(lane>>4)*8+j][ct*16+(lane&15)])
__global__ void k_pack(const float* __restrict__ src, f16* __restrict__ dst, int K, int Nc){
    int e = blockIdx.x*256 + threadIdx.x;
    if (e >= K*Nc) return;
    int j = e & 7;
    int lane = (e>>3) & 63;
    int tile = e >> 9;
    int nct = Nc >> 4;
    int ct = tile % nct;
    int kb = tile / nct;
    int k = kb*32 + ((lane>>4)<<3) + j;
    int n = ct*16 + (lane&15);
    dst[e] = (f16)src[k*Nc + n];
}

// ---------------- k_inflate3: MFMA inflate (VERIFIED r10; now writes v1 as f16)
__global__ __launch_bounds__(256) void k_inflate3(
    const float* __restrict__ hexf, const float* __restrict__ vertf,
    const int* __restrict__ v2h, const f16* __restrict__ BPinf,
    const float* __restrict__ b_inf, f16* __restrict__ v1h)
{
    const int tid = threadIdx.x;
    const int wave = tid>>6, lane = tid&63;
    const int l15 = lane&15, kg = lane>>4;
    const long tile0 = (long)(blockIdx.x*4 + wave)*16;
    const long ra = tile0 + l15;
    const int b = (int)(ra / NN);
    const int n = (int)(ra - (long)b*NN);
    const long hbase = (long)b*NT;
    int idx[3];
#pragma unroll
    for (int s=0;s<3;s++) idx[s] = v2h[n*3+s];

    f32x4 acc[8];
#pragma unroll
    for (int i=0;i<8;i++) acc[i]=(f32x4){0.f,0.f,0.f,0.f};

#pragma unroll
    for (int kb=0; kb<12; kb++){
        const int id = idx[kb>>2];
        f16x8 af = {0,0,0,0,0,0,0,0};
        if (id>=0){
            const float* p = hexf + ((hbase+id)*HD + (kb&3)*32 + kg*8);
            f32x4 x0 = *(const f32x4*)p;
            f32x4 x1 = *(const f32x4*)(p+4);
#pragma unroll
            for (int j=0;j<4;j++){ af[j]=(f16)x0[j]; af[4+j]=(f16)x1[j]; }
        }
#pragma unroll
        for (int ct=0; ct<8; ct++){
            f16x8 bf = *(const f16x8*)(BPinf + (((kb*8+ct)*64 + lane)<<3));
            acc[ct] = MFMA(af, bf, acc[ct]);
        }
    }
#pragma unroll
    for (int ct=0; ct<8; ct++){
        const int col = ct*16 + l15;
        const float bi = b_inf[col];
#pragma unroll
        for (int r=0;r<4;r++){
            const long row = tile0 + kg*4 + r;
            const long a = row*HD + col;
            v1h[a] = (f16)(acc[ct][r] + bi + vertf[a]);
        }
    }
}

// ---------------- k_vertex2: MFMA vertex path (structure VERIFIED r9-r11)
// r12: f16 v1, no restage (direct global A-frags, mechanism verified by k_inflate3),
//      Pf/IC aliased into x-region -> LDS 52224 B -> 3 blocks/CU
__global__ __launch_bounds__(256) void k_vertex2(
    const f16* __restrict__ v1h, const int* __restrict__ vadj,
    const f16* __restrict__ BPmsg, const float* __restrict__ b_msg,
    const f16* __restrict__ BPupd, const float* __restrict__ b_upd,
    const float* __restrict__ vng, const float* __restrict__ vnb,
    const f16* __restrict__ BPv1, const float* __restrict__ bv1,
    const f16* __restrict__ BPv2, const float* __restrict__ bv2,
    float* __restrict__ vout)
{
    __shared__ f16 lds[4*6528];
    const int tid=threadIdx.x, wave=tid>>6, lane=tid&63;
    const int l15=lane&15, kg=lane>>4;
    f16* Wl = lds + wave*6528;
    float* Wf = (float*)Wl;              // u region, pitch 133 f32: bytes [0,8512) < 8704
    float* Pf = (float*)(Wl + 4352);     // LN scratch: x-region bytes [8704,8960), dead before x writes
    float* IC = (float*)(Wl + 4352+128); // inv counts: x-region bytes [8960,9024), dead after s2
    const long tile0 = (long)(blockIdx.x*4+wave)*16;

    // s1: neighbor gather-sum -> s@0 (f16), inverse count
#pragma unroll 8
    for (int r=0;r<16;r++){
        const long row = tile0 + r;
        const int b = (int)(row / NN);
        const int n = (int)(row - (long)b*NN);
        float s0=0.f, s1=0.f; int cnt=0;
#pragma unroll
        for (int j=0;j<3;j++){
            const int idx = vadj[n*3+j];
            if (idx>=0){
                cnt++;
                const f16* p = v1h + ((long)(b*NN+idx)*HD + lane*2);
                s0 += (float)p[0]; s1 += (float)p[1];
            }
        }
        Wl[r*136 + lane*2]   = (f16)s0;
        Wl[r*136 + lane*2+1] = (f16)s1;
        if (lane==0) IC[r] = 1.0f/(float)(cnt<1?1:cnt);
    }

    f32x4 acc[8];
    // s2: agg = (s @ W_msg + 3*b_msg)/cnt -> agg@2176 (f16)
#pragma unroll
    for (int i=0;i<8;i++) acc[i]=(f32x4){0.f,0.f,0.f,0.f};
#pragma unroll
    for (int kb=0;kb<4;kb++){
        f16x8 af = *(const f16x8*)(Wl + l15*136 + kb*32 + kg*8);
#pragma unroll
        for (int ct=0;ct<8;ct++){
            f16x8 bf = *(const f16x8*)(BPmsg + (((kb*8+ct)*64+lane)<<3));
            acc[ct]=MFMA(af,bf,acc[ct]);
        }
    }
#pragma unroll
    for (int ct=0;ct<8;ct++){
        const int col = ct*16+l15;
        const float bm = 3.0f*b_msg[col];
#pragma unroll
        for (int r=0;r<4;r++){
            const int rl = kg*4+r;
            Wl[2176 + rl*136 + col] = (f16)((acc[ct][r]+bm)*IC[rl]);
        }
    }

    // s4: u_mat = [v1row, agg] @ W_upd ; v1row A-frags direct from global f16
#pragma unroll
    for (int i=0;i<8;i++) acc[i]=(f32x4){0.f,0.f,0.f,0.f};
#pragma unroll
    for (int kb=0;kb<8;kb++){
        f16x8 af;
        if (kb<4) af = *(const f16x8*)(v1h + (tile0+l15)*HD + kb*32 + kg*8);
        else      af = *(const f16x8*)(Wl + 2176 + l15*136 + (kb-4)*32 + kg*8);
#pragma unroll
        for (int ct=0;ct<8;ct++){
            f16x8 bf = *(const f16x8*)(BPupd + (((kb*8+ct)*64+lane)<<3));
            acc[ct]=MFMA(af,bf,acc[ct]);
        }
    }
    // s5: scatter u (f32) @0, pitch 133 — verified pairing with external residual
#pragma unroll
    for (int ct=0;ct<8;ct++){
        const int col=ct*16+l15;
        const float bu = b_upd[col];
#pragma unroll
        for (int r=0;r<4;r++){
            const int rl=kg*4+r;
            const long row=tile0+rl;
            Wf[rl*133 + col] = acc[ct][r] + bu + (float)v1h[row*HD+col];
        }
    }
    // s6: parallel LN — 4 lanes/row -> x@4352 (f16)
    {
        const int rr = lane>>2, q = lane&3;
        const float* Rf = Wf + rr*133 + q*32;
        f32x4 vv[8];
        float ps=0.f;
#pragma unroll
        for (int i=0;i<8;i++){
            vv[i] = *(const f32x4*)(Rf + i*4);
            ps += (vv[i][0]+vv[i][1])+(vv[i][2]+vv[i][3]);
        }
        Pf[lane]=ps;
        const float sum = Pf[rr*4]+Pf[rr*4+1]+Pf[rr*4+2]+Pf[rr*4+3];
        const float mu = sum*(1.f/HD);
        float pq=0.f;
#pragma unroll
        for (int i=0;i<8;i++){
#pragma unroll
            for (int j=0;j<4;j++){ const float d=vv[i][j]-mu; pq += d*d; }
        }
        Pf[lane]=pq;
        const float sq = Pf[rr*4]+Pf[rr*4+1]+Pf[rr*4+2]+Pf[rr*4+3];
        const float rstd = rsqrtf(sq*(1.f/HD)+1e-5f);
#pragma unroll
        for (int i=0;i<8;i++){
            f32x4 g4 = *(const f32x4*)(vng + q*32 + i*4);
            f32x4 b4 = *(const f32x4*)(vnb + q*32 + i*4);
            f16x4 o;
#pragma unroll
            for (int j=0;j<4;j++) o[j] = (f16)((vv[i][j]-mu)*rstd*g4[j]+b4[j]);
            *(f16x4*)(Wl + 4352 + rr*136 + q*32 + i*4) = o;
        }
    }

    // s7: h = gelu(x @ Wv1 + bv1) -> h@0 pitch 264 (u dead)
#pragma unroll
    for (int half=0; half<2; half++){
#pragma unroll
        for (int i=0;i<8;i++) acc[i]=(f32x4){0.f,0.f,0.f,0.f};
#pragma unroll
        for (int kb=0;kb<4;kb++){
            f16x8 af = *(const f16x8*)(Wl + 4352 + l15*136 + kb*32 + kg*8);
#pragma unroll
            for (int ct=0;ct<8;ct++){
                const int ctp = half*8+ct;
                f16x8 bf = *(const f16x8*)(BPv1 + (((kb*16+ctp)*64+lane)<<3));
                acc[ct]=MFMA(af,bf,acc[ct]);
            }
        }
#pragma unroll
        for (int ct=0;ct<8;ct++){
            const int colg = half*128 + ct*16 + l15;
            const float bb = bv1[colg];
#pragma unroll
            for (int r=0;r<4;r++){
                const int rl=kg*4+r;
                Wl[rl*264 + colg] = (f16)gelu_f(acc[ct][r]+bb);
            }
        }
    }

    // s8: y = x(LDS re-read) + h @ Wv2 + bv2 -> vout
#pragma unroll
    for (int i=0;i<8;i++) acc[i]=(f32x4){0.f,0.f,0.f,0.f};
#pragma unroll
    for (int kb=0;kb<8;kb++){
        f16x8 af = *(const f16x8*)(Wl + l15*264 + kb*32 + kg*8);
#pragma unroll
        for (int ct=0;ct<8;ct++){
            f16x8 bf = *(const f16x8*)(BPv2 + (((kb*8+ct)*64+lane)<<3));
            acc[ct]=MFMA(af,bf,acc[ct]);
        }
    }
#pragma unroll
    for (int ct=0;ct<8;ct++){
        const int col=ct*16+l15;
        const float bb=bv2[col];
#pragma unroll
        for (int r=0;r<4;r++){
            const int rl=kg*4+r;
            const long row=tile0+rl;
            vout[row*HD+col] = (float)Wl[4352+rl*136+col] + acc[ct][r] + bb;
        }
    }
}

// ---------------- k_hex2: MFMA hex path (same LDS-shrink upgrade)
__global__ __launch_bounds__(256) void k_hex2(
    const float* __restrict__ hexf, const float* __restrict__ vfin,
    const int* __restrict__ h2v,
    const f16* __restrict__ BPdef, const float* __restrict__ b_def,
    const float* __restrict__ hng, const float* __restrict__ hnb,
    const f16* __restrict__ BPh1, const float* __restrict__ bh1,
    const f16* __restrict__ BPh2, const float* __restrict__ bh2,
    float* __restrict__ hout)
{
    __shared__ f16 lds[4*6528];
    const int tid=threadIdx.x, wave=tid>>6, lane=tid&63;
    const int l15=lane&15, kg=lane>>4;
    f16* Wl = lds + wave*6528;
    float* Wf = (float*)Wl;
    float* Pf = (float*)(Wl + 4352);   // x-region scratch, dead before x writes
    const long tile0 = (long)(blockIdx.x*4+wave)*16;

    // s1: pooled = masked-mean of 6 vertex rows -> p@0 (f16)
#pragma unroll 4
    for (int r=0;r<16;r++){
        const long row = tile0 + r;
        const int b = (int)(row / NT);
        const int t = (int)(row - (long)b*NT);
        float s0=0.f, s1=0.f; int cnt=0;
#pragma unroll
        for (int j=0;j<6;j++){
            const int idx = h2v[t*6+j];
            if (idx>=0){
                cnt++;
                f32x2 p = *(const f32x2*)(vfin + ((long)(b*NN+idx)*HD + lane*2));
                s0 += p[0]; s1 += p[1];
            }
        }
        const float ic = 1.0f/(float)(cnt<1?1:cnt);
        Wl[r*136 + lane*2]   = (f16)(s0*ic);
        Wl[r*136 + lane*2+1] = (f16)(s1*ic);
    }

    f32x4 acc[8];
    // s2: deflated = p @ W_def
#pragma unroll
    for (int i=0;i<8;i++) acc[i]=(f32x4){0.f,0.f,0.f,0.f};
#pragma unroll
    for (int kb=0;kb<4;kb++){
        f16x8 af = *(const f16x8*)(Wl + l15*136 + kb*32 + kg*8);
#pragma unroll
        for (int ct=0;ct<8;ct++){
            f16x8 bf = *(const f16x8*)(BPdef + (((kb*8+ct)*64+lane)<<3));
            acc[ct]=MFMA(af,bf,acc[ct]);
        }
    }
    // scatter u (f32) @0, pitch 133 (p dead)
#pragma unroll
    for (int ct=0;ct<8;ct++){
        const int col=ct*16+l15;
        const float bd = b_def[col];
#pragma unroll
        for (int r=0;r<4;r++){
            const int rl=kg*4+r;
            const long row=tile0+rl;
            Wf[rl*133 + col] = acc[ct][r] + bd + hexf[row*HD+col];
        }
    }
    // s3: parallel LN -> x@4352
    {
        const int rr = lane>>2, q = lane&3;
        const float* Rf = Wf + rr*133 + q*32;
        f32x4 vv[8];
        float ps=0.f;
#pragma unroll
        for (int i=0;i<8;i++){
            vv[i] = *(const f32x4*)(Rf + i*4);
            ps += (vv[i][0]+vv[i][1])+(vv[i][2]+vv[i][3]);
        }
        Pf[lane]=ps;
        const float sum = Pf[rr*4]+Pf[rr*4+1]+Pf[rr*4+2]+Pf[rr*4+3];
        const float mu = sum*(1.f/HD);
        float pq=0.f;
#pragma unroll
        for (int i=0;i<8;i++){
#pragma unroll
            for (int j=0;j<4;j++){ const float d=vv[i][j]-mu; pq += d*d; }
        }
        Pf[lane]=pq;
        const float sq = Pf[rr*4]+Pf[rr*4+1]+Pf[rr*4+2]+Pf[rr*4+3];
        const float rstd = rsqrtf(sq*(1.f/HD)+1e-5f);
#pragma unroll
        for (int i=0;i<8;i++){
            f32x4 g4 = *(const f32x4*)(hng + q*32 + i*4);
            f32x4 b4 = *(const f32x4*)(hnb + q*32 + i*4);
            f16x4 o;
#pragma unroll
            for (int j=0;j<4;j++) o[j] = (f16)((vv[i][j]-mu)*rstd*g4[j]+b4[j]);
            *(f16x4*)(Wl + 4352 + rr*136 + q*32 + i*4) = o;
        }
    }

    // s4: h = gelu(x @ Wh1 + bh1) -> h@0 pitch 264
#pragma unroll
    for (int half=0; half<2; half++){
#pragma unroll
        for (int i=0;i<8;i++) acc[i]=(f32x4){0.f,0.f,0.f,0.f};
#pragma unroll
        for (int kb=0;kb<4;kb++){
            f16x8 af = *(const f16x8*)(Wl + 4352 + l15*136 + kb*32 + kg*8);
#pragma unroll
            for (int ct=0;ct<8;ct++){
                const int ctp = half*8+ct;
                f16x8 bf = *(const f16x8*)(BPh1 + (((kb*16+ctp)*64+lane)<<3));
                acc[ct]=MFMA(af,bf,acc[ct]);
            }
        }
#pragma unroll
        for (int ct=0;ct<8;ct++){
            const int colg = half*128 + ct*16 + l15;
            const float bb = bh1[colg];
#pragma unroll
            for (int r=0;r<4;r++){
                const int rl=kg*4+r;
                Wl[rl*264 + colg] = (f16)gelu_f(acc[ct][r]+bb);
            }
        }
    }

    // s5: out = x(LDS re-read) + h @ Wh2 + bh2 -> hout
#pragma unroll
    for (int i=0;i<8;i++) acc[i]=(f32x4){0.f,0.f,0.f,0.f};
#pragma unroll
    for (int kb=0;kb<8;kb++){
        f16x8 af = *(const f16x8*)(Wl + l15*264 + kb*32 + kg*8);
#pragma unroll
        for (int ct=0;ct<8;ct++){
            f16x8 bf = *(const f16x8*)(BPh2 + (((kb*8+ct)*64+lane)<<3));
            acc[ct]=MFMA(af,bf,acc[ct]);
        }
    }
#pragma unroll
    for (int ct=0;ct<8;ct++){
        const int col=ct*16+l15;
        const float bb=bh2[col];
#pragma unroll
        for (int r=0;r<4;r++){
            const int rl=kg*4+r;
            const long row=tile0+rl;
            hout[row*HD+col] = (float)Wl[4352+rl*136+col] + acc[ct][r] + bb;
        }
    }
}

extern "C" void kernel_launch(void* const* d_in, const int* in_sizes, int n_in,
                              void* d_out, int out_size, void* d_ws, size_t ws_size,
                              hipStream_t stream)
{
    (void)in_sizes; (void)n_in; (void)out_size; (void)ws_size;
    const float* hexf  = (const float*)d_in[0];
    const float* vertf = (const float*)d_in[1];
    const float* W_inf = (const float*)d_in[2];
    const float* b_inf = (const float*)d_in[3];
    const float* W_msg = (const float*)d_in[4];
    const float* b_msg = (const float*)d_in[5];
    const float* W_upd = (const float*)d_in[6];
    const float* b_upd = (const float*)d_in[7];
    const float* W_def = (const float*)d_in[8];
    const float* b_def = (const float*)d_in[9];
    const float* vng   = (const float*)d_in[10];
    const float* vnb   = (const float*)d_in[11];
    const float* hng   = (const float*)d_in[12];
    const float* hnb   = (const float*)d_in[13];
    const float* Wv1   = (const float*)d_in[14];
    const float* bv1   = (const float*)d_in[15];
    const float* Wv2   = (const float*)d_in[16];
    const float* bv2   = (const float*)d_in[17];
    const float* Wh1   = (const float*)d_in[18];
    const float* bh1   = (const float*)d_in[19];
    const float* Wh2   = (const float*)d_in[20];
    const float* bh2   = (const float*)d_in[21];
    const int* v2h   = (const int*)d_in[22];
    const int* h2v   = (const int*)d_in[23];
    const int* vadj  = (const int*)d_in[24];

    const long NV = (long)NB*NN;                 // 240000 vertex rows
    f16* v1h = (f16*)d_ws;                       // 61.44 MB
    f16* packs = (f16*)((char*)d_ws + (size_t)NV*HD*2);
    f16* BPinf = packs;                // 384*128
    f16* BPmsg = BPinf + 384*128;      // 128*128
    f16* BPupd = BPmsg + 128*128;      // 256*128
    f16* BPdef = BPupd + 256*128;      // 128*128
    f16* BPv1  = BPdef + 128*128;      // 128*256
    f16* BPv2  = BPv1 + 128*256;       // 256*128
    f16* BPh1  = BPv2 + 256*128;       // 128*256
    f16* BPh2  = BPh1 + 128*256;       // 256*128

    k_pack<<<(384*128)/256,256,0,stream>>>(W_inf, BPinf, 384,128);
    k_pack<<<(128*128)/256,256,0,stream>>>(W_msg, BPmsg, 128,128);
    k_pack<<<(256*128)/256,256,0,stream>>>(W_upd, BPupd, 256,128);
    k_pack<<<(128*128)/256,256,0,stream>>>(W_def, BPdef, 128,128);
    k_pack<<<(128*256)/256,256,0,stream>>>(Wv1,  BPv1, 128,256);
    k_pack<<<(256*128)/256,256,0,stream>>>(Wv2,  BPv2, 256,128);
    k_pack<<<(128*256)/256,256,0,stream>>>(Wh1,  BPh1, 128,256);
    k_pack<<<(256*128)/256,256,0,stream>>>(Wh2,  BPh2, 256,128);

    float* hout = (float*)d_out;
    float* vout = hout + (long)NB*NT*HD;

    k_inflate3<<<3750,256,0,stream>>>(hexf, vertf, v2h, BPinf, b_inf, v1h);
    k_vertex2<<<3750,256,0,stream>>>(v1h, vadj, BPmsg, b_msg, BPupd, b_upd,
                                     vng, vnb, BPv1, bv1, BPv2, bv2, vout);
    k_hex2<<<1250,256,0,stream>>>(hexf, vout, h2v, BPdef, b_def, hng, hnb,
                                  BPh1, bh1, BPh2, bh2, hout);
}

// Round 13
// 608.418 us; speedup vs baseline: 11.5127x; 1.1581x over previous
//
#include <hip/hip_runtime.h>
#include <math.h>

typedef _Float16 f16;
typedef __attribute__((ext_vector_type(8))) _Float16 f16x8;
typedef __attribute__((ext_vector_type(4))) _Float16 f16x4;
typedef __attribute__((ext_vector_type(4))) float f32x4;
typedef __attribute__((ext_vector_type(2))) float f32x2;

#define NB 4
#define NT 20000
#define NN 60000
#define HD 128

#define MFMA(a,b,c) __builtin_amdgcn_mfma_f32_16x16x32_f16((a),(b),(c),0,0,0)

__device__ __forceinline__ float gelu_f(float t){
    return 0.5f*t*(1.0f+erff(t*0.70710678118654752f));
}

// ---------- fused pack: all 8 weights -> f16 MFMA B-frag order, one launch
// dst[((kb*NCT+ct)*64+lane)*8 + j] = f16(W[kb*32+(lane>>4)*8+j][ct*16+(lane&15)])
struct PackArgs {
    const float* src[8];
    int K[8], Nc[8], off[8];   // off = dst offset (elems)
};
__global__ __launch_bounds__(256) void k_pack_all(PackArgs pa, f16* __restrict__ dst){
    int e = blockIdx.x*256 + threadIdx.x;
    if (e >= 245760) return;
    int s = 0;
#pragma unroll
    for (int i=1;i<8;i++) if (e >= pa.off[i]) s = i;
    const int el = e - pa.off[s];
    const int K = pa.K[s], Nc = pa.Nc[s];
    const float* src = pa.src[s];
    int j = el & 7;
    int lane = (el>>3) & 63;
    int tile = el >> 9;
    int nct = Nc >> 4;
    int ct = tile % nct;
    int kb = tile / nct;
    int k = kb*32 + ((lane>>4)<<3) + j;
    int n = ct*16 + (lane&15);
    dst[e] = (f16)src[k*Nc + n];
}

// ---------------- k_inflate3: MFMA inflate (VERIFIED r10-r12 — unchanged)
__global__ __launch_bounds__(256) void k_inflate3(
    const float* __restrict__ hexf, const float* __restrict__ vertf,
    const int* __restrict__ v2h, const f16* __restrict__ BPinf,
    const float* __restrict__ b_inf, f16* __restrict__ v1h)
{
    const int tid = threadIdx.x;
    const int wave = tid>>6, lane = tid&63;
    const int l15 = lane&15, kg = lane>>4;
    const long tile0 = (long)(blockIdx.x*4 + wave)*16;
    const long ra = tile0 + l15;
    const int b = (int)(ra / NN);
    const int n = (int)(ra - (long)b*NN);
    const long hbase = (long)b*NT;
    int idx[3];
#pragma unroll
    for (int s=0;s<3;s++) idx[s] = v2h[n*3+s];

    f32x4 acc[8];
#pragma unroll
    for (int i=0;i<8;i++) acc[i]=(f32x4){0.f,0.f,0.f,0.f};

#pragma unroll
    for (int kb=0; kb<12; kb++){
        const int id = idx[kb>>2];
        f16x8 af = {0,0,0,0,0,0,0,0};
        if (id>=0){
            const float* p = hexf + ((hbase+id)*HD + (kb&3)*32 + kg*8);
            f32x4 x0 = *(const f32x4*)p;
            f32x4 x1 = *(const f32x4*)(p+4);
#pragma unroll
            for (int j=0;j<4;j++){ af[j]=(f16)x0[j]; af[4+j]=(f16)x1[j]; }
        }
#pragma unroll
        for (int ct=0; ct<8; ct++){
            f16x8 bf = *(const f16x8*)(BPinf + (((kb*8+ct)*64 + lane)<<3));
            acc[ct] = MFMA(af, bf, acc[ct]);
        }
    }
#pragma unroll
    for (int ct=0; ct<8; ct++){
        const int col = ct*16 + l15;
        const float bi = b_inf[col];
#pragma unroll
        for (int r=0;r<4;r++){
            const long row = tile0 + kg*4 + r;
            const long a = row*HD + col;
            v1h[a] = (f16)(acc[ct][r] + bi + vertf[a]);
        }
    }
}

// ---------------- k_vertex3: 8704 B/wave LDS, register-resident u, scratch-LN
// regions per wave (f16 idx): R0@0 [16][136] (s -> x), R1@2176 [16][136] (agg -> LNscratch -> h_half)
__global__ __launch_bounds__(256,4) void k_vertex3(
    const f16* __restrict__ v1h, const int* __restrict__ vadj,
    const f16* __restrict__ BPmsg, const float* __restrict__ b_msg,
    const f16* __restrict__ BPupd, const float* __restrict__ b_upd,
    const float* __restrict__ vng, const float* __restrict__ vnb,
    const f16* __restrict__ BPv1, const float* __restrict__ bv1,
    const f16* __restrict__ BPv2, const float* __restrict__ bv2,
    float* __restrict__ vout)
{
    __shared__ f16 lds[4*4352];
    __shared__ float ics[4*16];
    const int tid=threadIdx.x, wave=tid>>6, lane=tid&63;
    const int l15=lane&15, kg=lane>>4;
    f16* Wl = lds + wave*4352;           // R0
    f16* R1 = Wl + 2176;
    float* scr = (float*)R1;             // LN scratch: prs[16][16] @0, mu[16]@256, rsd[16]@272 (f32 idx)
    float* IC = ics + wave*16;
    const long tile0 = (long)(blockIdx.x*4+wave)*16;

    // s1: neighbor gather-sum -> R0 (f16), inverse count
#pragma unroll 8
    for (int r=0;r<16;r++){
        const long row = tile0 + r;
        const int b = (int)(row / NN);
        const int n = (int)(row - (long)b*NN);
        float s0=0.f, s1=0.f; int cnt=0;
#pragma unroll
        for (int j=0;j<3;j++){
            const int idx = vadj[n*3+j];
            if (idx>=0){
                cnt++;
                const f16* p = v1h + ((long)(b*NN+idx)*HD + lane*2);
                s0 += (float)p[0]; s1 += (float)p[1];
            }
        }
        Wl[r*136 + lane*2]   = (f16)s0;
        Wl[r*136 + lane*2+1] = (f16)s1;
        if (lane==0) IC[r] = 1.0f/(float)(cnt<1?1:cnt);
    }

    f32x4 acc[8];
    // s2: agg = (s @ W_msg + 3*b_msg)/cnt -> R1 (f16)
#pragma unroll
    for (int i=0;i<8;i++) acc[i]=(f32x4){0.f,0.f,0.f,0.f};
#pragma unroll
    for (int kb=0;kb<4;kb++){
        f16x8 af = *(const f16x8*)(Wl + l15*136 + kb*32 + kg*8);
#pragma unroll
        for (int ct=0;ct<8;ct++){
            f16x8 bf = *(const f16x8*)(BPmsg + (((kb*8+ct)*64+lane)<<3));
            acc[ct]=MFMA(af,bf,acc[ct]);
        }
    }
#pragma unroll
    for (int ct=0;ct<8;ct++){
        const int col = ct*16+l15;
        const float bm = 3.0f*b_msg[col];
#pragma unroll
        for (int r=0;r<4;r++){
            const int rl = kg*4+r;
            R1[rl*136 + col] = (f16)((acc[ct][r]+bm)*IC[rl]);
        }
    }

    // s4: u = [v1row(global), agg@R1] @ W_upd -> acc
#pragma unroll
    for (int i=0;i<8;i++) acc[i]=(f32x4){0.f,0.f,0.f,0.f};
#pragma unroll
    for (int kb=0;kb<8;kb++){
        f16x8 af;
        if (kb<4) af = *(const f16x8*)(v1h + (tile0+l15)*HD + kb*32 + kg*8);
        else      af = *(const f16x8*)(R1 + l15*136 + (kb-4)*32 + kg*8);
#pragma unroll
        for (int ct=0;ct<8;ct++){
            f16x8 bf = *(const f16x8*)(BPupd + (((kb*8+ct)*64+lane)<<3));
            acc[ct]=MFMA(af,bf,acc[ct]);
        }
    }
    // u := acc + b_upd + residual (registers; verified arithmetic from r9 s5)
#pragma unroll
    for (int ct=0;ct<8;ct++){
        const int col=ct*16+l15;
        const float bu = b_upd[col];
#pragma unroll
        for (int r=0;r<4;r++)
            acc[ct][r] += bu + (float)v1h[(tile0+kg*4+r)*HD+col];
    }
    // LN via LDS-scratch partials (agg dead -> scr @ R1)
    float mu_r[4], rs_r[4];
    {
#pragma unroll
        for (int r=0;r<4;r++){
            float ps=0.f;
#pragma unroll
            for (int ct=0;ct<8;ct++) ps += acc[ct][r];
            scr[(kg*4+r)*16 + l15] = ps;
        }
        if (lane<16){
            float s=0.f;
#pragma unroll
            for (int i=0;i<4;i++){
                f32x4 v = *(const f32x4*)(scr + lane*16 + i*4);
                s += (v[0]+v[1])+(v[2]+v[3]);
            }
            scr[256+lane] = s*(1.f/HD);
        }
#pragma unroll
        for (int r=0;r<4;r++) mu_r[r] = scr[256+kg*4+r];
#pragma unroll
        for (int r=0;r<4;r++){
            float pq=0.f;
#pragma unroll
            for (int ct=0;ct<8;ct++){ const float d=acc[ct][r]-mu_r[r]; pq += d*d; }
            scr[(kg*4+r)*16 + l15] = pq;
        }
        if (lane<16){
            float s=0.f;
#pragma unroll
            for (int i=0;i<4;i++){
                f32x4 v = *(const f32x4*)(scr + lane*16 + i*4);
                s += (v[0]+v[1])+(v[2]+v[3]);
            }
            scr[272+lane] = rsqrtf(s*(1.f/HD)+1e-5f);
        }
#pragma unroll
        for (int r=0;r<4;r++) rs_r[r] = scr[272+kg*4+r];
    }
    // x -> R0 (s dead after s2); C/D-addressed write (verified pattern)
#pragma unroll
    for (int ct=0;ct<8;ct++){
        const int col=ct*16+l15;
        const float g = vng[col], bb = vnb[col];
#pragma unroll
        for (int r=0;r<4;r++){
            const int rl=kg*4+r;
            Wl[rl*136 + col] = (f16)((acc[ct][r]-mu_r[r])*rs_r[r]*g + bb);
        }
    }

    // MLP with h-half split: h_half -> R1 (scratch dead), y accumulates in acc_y
    f32x4 acc_y[8];
#pragma unroll
    for (int i=0;i<8;i++) acc_y[i]=(f32x4){0.f,0.f,0.f,0.f};
#pragma unroll
    for (int half=0; half<2; half++){
#pragma unroll
        for (int i=0;i<8;i++) acc[i]=(f32x4){0.f,0.f,0.f,0.f};
#pragma unroll
        for (int kb=0;kb<4;kb++){
            f16x8 af = *(const f16x8*)(Wl + l15*136 + kb*32 + kg*8);
#pragma unroll
            for (int ct=0;ct<8;ct++){
                const int ctp = half*8+ct;
                f16x8 bf = *(const f16x8*)(BPv1 + (((kb*16+ctp)*64+lane)<<3));
                acc[ct]=MFMA(af,bf,acc[ct]);
            }
        }
#pragma unroll
        for (int ct=0;ct<8;ct++){
            const int colg = half*128 + ct*16 + l15;
            const float bb = bv1[colg];
#pragma unroll
            for (int r=0;r<4;r++){
                const int rl=kg*4+r;
                R1[rl*136 + ct*16+l15] = (f16)gelu_f(acc[ct][r]+bb);
            }
        }
#pragma unroll
        for (int kb=0;kb<4;kb++){
            f16x8 af = *(const f16x8*)(R1 + l15*136 + kb*32 + kg*8);
#pragma unroll
            for (int ct=0;ct<8;ct++){
                f16x8 bf = *(const f16x8*)(BPv2 + ((((half*4+kb)*8+ct)*64+lane)<<3));
                acc_y[ct]=MFMA(af,bf,acc_y[ct]);
            }
        }
    }
    // y = x(R0 re-read) + acc_y + bv2
#pragma unroll
    for (int ct=0;ct<8;ct++){
        const int col=ct*16+l15;
        const float bb=bv2[col];
#pragma unroll
        for (int r=0;r<4;r++){
            const int rl=kg*4+r;
            vout[(tile0+rl)*HD+col] = (float)Wl[rl*136+col] + acc_y[ct][r] + bb;
        }
    }
}

// ---------------- k_hex3: same restructure for hex path
__global__ __launch_bounds__(256,4) void k_hex3(
    const float* __restrict__ hexf, const float* __restrict__ vfin,
    const int* __restrict__ h2v,
    const f16* __restrict__ BPdef, const float* __restrict__ b_def,
    const float* __restrict__ hng, const float* __restrict__ hnb,
    const f16* __restrict__ BPh1, const float* __restrict__ bh1,
    const f16* __restrict__ BPh2, const float* __restrict__ bh2,
    float* __restrict__ hout)
{
    __shared__ f16 lds[4*4352];
    const int tid=threadIdx.x, wave=tid>>6, lane=tid&63;
    const int l15=lane&15, kg=lane>>4;
    f16* Wl = lds + wave*4352;
    f16* R1 = Wl + 2176;
    float* scr = (float*)R1;
    const long tile0 = (long)(blockIdx.x*4+wave)*16;

    // s1: pooled = masked-mean of 6 vertex rows -> R0 (f16)
#pragma unroll 4
    for (int r=0;r<16;r++){
        const long row = tile0 + r;
        const int b = (int)(row / NT);
        const int t = (int)(row - (long)b*NT);
        float s0=0.f, s1=0.f; int cnt=0;
#pragma unroll
        for (int j=0;j<6;j++){
            const int idx = h2v[t*6+j];
            if (idx>=0){
                cnt++;
                f32x2 p = *(const f32x2*)(vfin + ((long)(b*NN+idx)*HD + lane*2));
                s0 += p[0]; s1 += p[1];
            }
        }
        const float ic = 1.0f/(float)(cnt<1?1:cnt);
        Wl[r*136 + lane*2]   = (f16)(s0*ic);
        Wl[r*136 + lane*2+1] = (f16)(s1*ic);
    }

    f32x4 acc[8];
    // s2: deflated = p @ W_def -> acc ; += b_def + hex residual
#pragma unroll
    for (int i=0;i<8;i++) acc[i]=(f32x4){0.f,0.f,0.f,0.f};
#pragma unroll
    for (int kb=0;kb<4;kb++){
        f16x8 af = *(const f16x8*)(Wl + l15*136 + kb*32 + kg*8);
#pragma unroll
        for (int ct=0;ct<8;ct++){
            f16x8 bf = *(const f16x8*)(BPdef + (((kb*8+ct)*64+lane)<<3));
            acc[ct]=MFMA(af,bf,acc[ct]);
        }
    }
#pragma unroll
    for (int ct=0;ct<8;ct++){
        const int col=ct*16+l15;
        const float bd = b_def[col];
#pragma unroll
        for (int r=0;r<4;r++)
            acc[ct][r] += bd + hexf[(tile0+kg*4+r)*HD+col];
    }
    // LN via scratch (R1 free: p-region? no — p is R0. R1 unused so far) -> x to R0 (p dead)
    float mu_r[4], rs_r[4];
    {
#pragma unroll
        for (int r=0;r<4;r++){
            float ps=0.f;
#pragma unroll
            for (int ct=0;ct<8;ct++) ps += acc[ct][r];
            scr[(kg*4+r)*16 + l15] = ps;
        }
        if (lane<16){
            float s=0.f;
#pragma unroll
            for (int i=0;i<4;i++){
                f32x4 v = *(const f32x4*)(scr + lane*16 + i*4);
                s += (v[0]+v[1])+(v[2]+v[3]);
            }
            scr[256+lane] = s*(1.f/HD);
        }
#pragma unroll
        for (int r=0;r<4;r++) mu_r[r] = scr[256+kg*4+r];
#pragma unroll
        for (int r=0;r<4;r++){
            float pq=0.f;
#pragma unroll
            for (int ct=0;ct<8;ct++){ const float d=acc[ct][r]-mu_r[r]; pq += d*d; }
            scr[(kg*4+r)*16 + l15] = pq;
        }
        if (lane<16){
            float s=0.f;
#pragma unroll
            for (int i=0;i<4;i++){
                f32x4 v = *(const f32x4*)(scr + lane*16 + i*4);
                s += (v[0]+v[1])+(v[2]+v[3]);
            }
            scr[272+lane] = rsqrtf(s*(1.f/HD)+1e-5f);
        }
#pragma unroll
        for (int r=0;r<4;r++) rs_r[r] = scr[272+kg*4+r];
    }
#pragma unroll
    for (int ct=0;ct<8;ct++){
        const int col=ct*16+l15;
        const float g = hng[col], bb = hnb[col];
#pragma unroll
        for (int r=0;r<4;r++){
            const int rl=kg*4+r;
            Wl[rl*136 + col] = (f16)((acc[ct][r]-mu_r[r])*rs_r[r]*g + bb);
        }
    }

    // MLP h-half split
    f32x4 acc_y[8];
#pragma unroll
    for (int i=0;i<8;i++) acc_y[i]=(f32x4){0.f,0.f,0.f,0.f};
#pragma unroll
    for (int half=0; half<2; half++){
#pragma unroll
        for (int i=0;i<8;i++) acc[i]=(f32x4){0.f,0.f,0.f,0.f};
#pragma unroll
        for (int kb=0;kb<4;kb++){
            f16x8 af = *(const f16x8*)(Wl + l15*136 + kb*32 + kg*8);
#pragma unroll
            for (int ct=0;ct<8;ct++){
                const int ctp = half*8+ct;
                f16x8 bf = *(const f16x8*)(BPh1 + (((kb*16+ctp)*64+lane)<<3));
                acc[ct]=MFMA(af,bf,acc[ct]);
            }
        }
#pragma unroll
        for (int ct=0;ct<8;ct++){
            const int colg = half*128 + ct*16 + l15;
            const float bb = bh1[colg];
#pragma unroll
            for (int r=0;r<4;r++){
                const int rl=kg*4+r;
                R1[rl*136 + ct*16+l15] = (f16)gelu_f(acc[ct][r]+bb);
            }
        }
#pragma unroll
        for (int kb=0;kb<4;kb++){
            f16x8 af = *(const f16x8*)(R1 + l15*136 + kb*32 + kg*8);
#pragma unroll
            for (int ct=0;ct<8;ct++){
                f16x8 bf = *(const f16x8*)(BPh2 + ((((half*4+kb)*8+ct)*64+lane)<<3));
                acc_y[ct]=MFMA(af,bf,acc_y[ct]);
            }
        }
    }
#pragma unroll
    for (int ct=0;ct<8;ct++){
        const int col=ct*16+l15;
        const float bb=bh2[col];
#pragma unroll
        for (int r=0;r<4;r++){
            const int rl=kg*4+r;
            hout[(tile0+rl)*HD+col] = (float)Wl[rl*136+col] + acc_y[ct][r] + bb;
        }
    }
}

extern "C" void kernel_launch(void* const* d_in, const int* in_sizes, int n_in,
                              void* d_out, int out_size, void* d_ws, size_t ws_size,
                              hipStream_t stream)
{
    (void)in_sizes; (void)n_in; (void)out_size; (void)ws_size;
    const float* hexf  = (const float*)d_in[0];
    const float* vertf = (const float*)d_in[1];
    const float* W_inf = (const float*)d_in[2];
    const float* b_inf = (const float*)d_in[3];
    const float* W_msg = (const float*)d_in[4];
    const float* b_msg = (const float*)d_in[5];
    const float* W_upd = (const float*)d_in[6];
    const float* b_upd = (const float*)d_in[7];
    const float* W_def = (const float*)d_in[8];
    const float* b_def = (const float*)d_in[9];
    const float* vng   = (const float*)d_in[10];
    const float* vnb   = (const float*)d_in[11];
    const float* hng   = (const float*)d_in[12];
    const float* hnb   = (const float*)d_in[13];
    const float* Wv1   = (const float*)d_in[14];
    const float* bv1   = (const float*)d_in[15];
    const float* Wv2   = (const float*)d_in[16];
    const float* bv2   = (const float*)d_in[17];
    const float* Wh1   = (const float*)d_in[18];
    const float* bh1   = (const float*)d_in[19];
    const float* Wh2   = (const float*)d_in[20];
    const float* bh2   = (const float*)d_in[21];
    const int* v2h   = (const int*)d_in[22];
    const int* h2v   = (const int*)d_in[23];
    const int* vadj  = (const int*)d_in[24];

    const long NV = (long)NB*NN;                 // 240000 vertex rows
    f16* v1h = (f16*)d_ws;                       // 61.44 MB
    f16* packs = (f16*)((char*)d_ws + (size_t)NV*HD*2);
    f16* BPinf = packs;                // off 0       (384x128)
    f16* BPmsg = BPinf + 49152;        // off 49152   (128x128)
    f16* BPupd = BPmsg + 16384;        // off 65536   (256x128)
    f16* BPdef = BPupd + 32768;        // off 98304   (128x128)
    f16* BPv1  = BPdef + 16384;        // off 114688  (128x256)
    f16* BPv2  = BPv1 + 32768;         // off 147456  (256x128)
    f16* BPh1  = BPv2 + 32768;         // off 180224  (128x256)
    f16* BPh2  = BPh1 + 32768;         // off 212992  (256x128)

    PackArgs pa;
    pa.src[0]=W_inf; pa.K[0]=384; pa.Nc[0]=128; pa.off[0]=0;
    pa.src[1]=W_msg; pa.K[1]=128; pa.Nc[1]=128; pa.off[1]=49152;
    pa.src[2]=W_upd; pa.K[2]=256; pa.Nc[2]=128; pa.off[2]=65536;
    pa.src[3]=W_def; pa.K[3]=128; pa.Nc[3]=128; pa.off[3]=98304;
    pa.src[4]=Wv1;   pa.K[4]=128; pa.Nc[4]=256; pa.off[4]=114688;
    pa.src[5]=Wv2;   pa.K[5]=256; pa.Nc[5]=128; pa.off[5]=147456;
    pa.src[6]=Wh1;   pa.K[6]=128; pa.Nc[6]=256; pa.off[6]=180224;
    pa.src[7]=Wh2;   pa.K[7]=256; pa.Nc[7]=128; pa.off[7]=212992;
    k_pack_all<<<960,256,0,stream>>>(pa, packs);

    float* hout = (float*)d_out;
    float* vout = hout + (long)NB*NT*HD;

    k_inflate3<<<3750,256,0,stream>>>(hexf, vertf, v2h, BPinf, b_inf, v1h);
    k_vertex3<<<3750,256,0,stream>>>(v1h, vadj, BPmsg, b_msg, BPupd, b_upd,
                                     vng, vnb, BPv1, bv1, BPv2, bv2, vout);
    k_hex3<<<1250,256,0,stream>>>(hexf, vout, h2v, BPdef, b_def, hng, hnb,
                                  BPh1, bh1, BPh2, bh2, hout);
}

// Round 14
// 547.119 us; speedup vs baseline: 12.8026x; 1.1120x over previous
//
#include <hip/hip_runtime.h>
#include <math.h>

typedef _Float16 f16;
typedef __attribute__((ext_vector_type(8))) _Float16 f16x8;
typedef __attribute__((ext_vector_type(4))) _Float16 f16x4;
typedef __attribute__((ext_vector_type(2))) _Float16 f16x2;
typedef __attribute__((ext_vector_type(4))) float f32x4;
typedef __attribute__((ext_vector_type(2))) float f32x2;

#define NB 4
#define NT 20000
#define NN 60000
#define HD 128

#define MFMA(a,b,c) __builtin_amdgcn_mfma_f32_16x16x32_f16((a),(b),(c),0,0,0)

__device__ __forceinline__ float gelu_f(float t){
    return 0.5f*t*(1.0f+erff(t*0.70710678118654752f));
}

// ---------- fused pack: all 8 weights -> f16 MFMA B-frag order, one launch
struct PackArgs {
    const float* src[8];
    int K[8], Nc[8], off[8];
};
__global__ __launch_bounds__(256) void k_pack_all(PackArgs pa, f16* __restrict__ dst){
    int e = blockIdx.x*256 + threadIdx.x;
    if (e >= 245760) return;
    int s = 0;
#pragma unroll
    for (int i=1;i<8;i++) if (e >= pa.off[i]) s = i;
    const int el = e - pa.off[s];
    const int Nc = pa.Nc[s];
    const float* src = pa.src[s];
    int j = el & 7;
    int lane = (el>>3) & 63;
    int tile = el >> 9;
    int nct = Nc >> 4;
    int ct = tile % nct;
    int kb = tile / nct;
    int k = kb*32 + ((lane>>4)<<3) + j;
    int n = ct*16 + (lane&15);
    dst[e] = (f16)src[k*Nc + n];
}

// ---------------- k_inflate4: MFMA inflate; vertf residual staged in LDS (coalesced)
__global__ __launch_bounds__(256) void k_inflate4(
    const float* __restrict__ hexf, const float* __restrict__ vertf,
    const int* __restrict__ v2h, const f16* __restrict__ BPinf,
    const float* __restrict__ b_inf, f16* __restrict__ v1h)
{
    __shared__ float Vst[4*2112];        // per wave: [16][132] f32
    const int tid = threadIdx.x;
    const int wave = tid>>6, lane = tid&63;
    const int l15 = lane&15, kg = lane>>4;
    float* Vf = Vst + wave*2112;
    const long tile0 = (long)(blockIdx.x*4 + wave)*16;
    const long ra = tile0 + l15;
    const int b = (int)(ra / NN);
    const int n = (int)(ra - (long)b*NN);
    const long hbase = (long)b*NT;
    int idx[3];
#pragma unroll
    for (int s=0;s<3;s++) idx[s] = v2h[n*3+s];

    // stage own vertf rows (coalesced 8B loads)
#pragma unroll 8
    for (int r=0;r<16;r++){
        f32x2 v = *(const f32x2*)(vertf + (tile0+r)*HD + lane*2);
        Vf[r*132 + lane*2]   = v[0];
        Vf[r*132 + lane*2+1] = v[1];
    }

    f32x4 acc[8];
#pragma unroll
    for (int i=0;i<8;i++) acc[i]=(f32x4){0.f,0.f,0.f,0.f};

#pragma unroll
    for (int kb=0; kb<12; kb++){
        const int id = idx[kb>>2];
        f16x8 af = {0,0,0,0,0,0,0,0};
        if (id>=0){
            const float* p = hexf + ((hbase+id)*HD + (kb&3)*32 + kg*8);
            f32x4 x0 = *(const f32x4*)p;
            f32x4 x1 = *(const f32x4*)(p+4);
#pragma unroll
            for (int j=0;j<4;j++){ af[j]=(f16)x0[j]; af[4+j]=(f16)x1[j]; }
        }
#pragma unroll
        for (int ct=0; ct<8; ct++){
            f16x8 bf = *(const f16x8*)(BPinf + (((kb*8+ct)*64 + lane)<<3));
            acc[ct] = MFMA(af, bf, acc[ct]);
        }
    }
#pragma unroll
    for (int ct=0; ct<8; ct++){
        const int col = ct*16 + l15;
        const float bi = b_inf[col];
#pragma unroll
        for (int r=0;r<4;r++){
            const int rl = kg*4+r;
            const long row = tile0 + rl;
            v1h[row*HD + col] = (f16)(acc[ct][r] + bi + Vf[rl*132 + col]);
        }
    }
}

// ---------------- k_vertex4: all own-row traffic via LDS; regions R0/R1 time-shared
// R0: s -> agg -> x ; R1: own-rows -> LNscratch -> h_half   (8704 B/wave)
__global__ __launch_bounds__(256,4) void k_vertex4(
    const f16* __restrict__ v1h, const int* __restrict__ vadj,
    const f16* __restrict__ BPmsg, const float* __restrict__ b_msg,
    const f16* __restrict__ BPupd, const float* __restrict__ b_upd,
    const float* __restrict__ vng, const float* __restrict__ vnb,
    const f16* __restrict__ BPv1, const float* __restrict__ bv1,
    const f16* __restrict__ BPv2, const float* __restrict__ bv2,
    float* __restrict__ vout)
{
    __shared__ f16 lds[4*4352];
    __shared__ float ics[4*16];
    const int tid=threadIdx.x, wave=tid>>6, lane=tid&63;
    const int l15=lane&15, kg=lane>>4;
    f16* R0 = lds + wave*4352;
    f16* R1 = R0 + 2176;
    float* scr = (float*)R1;
    float* IC = ics + wave*16;
    const long tile0 = (long)(blockIdx.x*4+wave)*16;

    // s1: neighbor gather-sum -> R0, own-row stage -> R1, counts
#pragma unroll 8
    for (int r=0;r<16;r++){
        const long row = tile0 + r;
        const int b = (int)(row / NN);
        const int n = (int)(row - (long)b*NN);
        f16x2 own = *(const f16x2*)(v1h + row*HD + lane*2);
        float s0=0.f, s1=0.f; int cnt=0;
#pragma unroll
        for (int j=0;j<3;j++){
            const int idx = vadj[n*3+j];
            if (idx>=0){
                cnt++;
                f16x2 p = *(const f16x2*)(v1h + ((long)(b*NN+idx)*HD + lane*2));
                s0 += (float)p[0]; s1 += (float)p[1];
            }
        }
        *(f16x2*)(R0 + r*136 + lane*2) = (f16x2){(f16)s0,(f16)s1};
        *(f16x2*)(R1 + r*136 + lane*2) = own;
        if (lane==0) IC[r] = 1.0f/(float)(cnt<1?1:cnt);
    }

    f32x4 acc[8];
    // s2: agg = (s @ W_msg + 3*b_msg)/cnt -> R0 (in-order LDS: reads precede writes)
#pragma unroll
    for (int i=0;i<8;i++) acc[i]=(f32x4){0.f,0.f,0.f,0.f};
#pragma unroll
    for (int kb=0;kb<4;kb++){
        f16x8 af = *(const f16x8*)(R0 + l15*136 + kb*32 + kg*8);
#pragma unroll
        for (int ct=0;ct<8;ct++){
            f16x8 bf = *(const f16x8*)(BPmsg + (((kb*8+ct)*64+lane)<<3));
            acc[ct]=MFMA(af,bf,acc[ct]);
        }
    }
#pragma unroll
    for (int ct=0;ct<8;ct++){
        const int col = ct*16+l15;
        const float bm = 3.0f*b_msg[col];
#pragma unroll
        for (int r=0;r<4;r++){
            const int rl = kg*4+r;
            R0[rl*136 + col] = (f16)((acc[ct][r]+bm)*IC[rl]);
        }
    }

    // s4: u = [own(R1), agg(R0)] @ W_upd -> acc ; += b_upd + residual(R1)
#pragma unroll
    for (int i=0;i<8;i++) acc[i]=(f32x4){0.f,0.f,0.f,0.f};
#pragma unroll
    for (int kb=0;kb<8;kb++){
        f16x8 af;
        if (kb<4) af = *(const f16x8*)(R1 + l15*136 + kb*32 + kg*8);
        else      af = *(const f16x8*)(R0 + l15*136 + (kb-4)*32 + kg*8);
#pragma unroll
        for (int ct=0;ct<8;ct++){
            f16x8 bf = *(const f16x8*)(BPupd + (((kb*8+ct)*64+lane)<<3));
            acc[ct]=MFMA(af,bf,acc[ct]);
        }
    }
#pragma unroll
    for (int ct=0;ct<8;ct++){
        const int col=ct*16+l15;
        const float bu = b_upd[col];
#pragma unroll
        for (int r=0;r<4;r++)
            acc[ct][r] += bu + (float)R1[(kg*4+r)*136 + col];
    }
    // LN via scratch @R1 (own dead after residual reads; in-order LDS)
    float mu_r[4], rs_r[4];
    {
#pragma unroll
        for (int r=0;r<4;r++){
            float ps=0.f;
#pragma unroll
            for (int ct=0;ct<8;ct++) ps += acc[ct][r];
            scr[(kg*4+r)*16 + l15] = ps;
        }
        if (lane<16){
            float s=0.f;
#pragma unroll
            for (int i=0;i<4;i++){
                f32x4 v = *(const f32x4*)(scr + lane*16 + i*4);
                s += (v[0]+v[1])+(v[2]+v[3]);
            }
            scr[256+lane] = s*(1.f/HD);
        }
#pragma unroll
        for (int r=0;r<4;r++) mu_r[r] = scr[256+kg*4+r];
#pragma unroll
        for (int r=0;r<4;r++){
            float pq=0.f;
#pragma unroll
            for (int ct=0;ct<8;ct++){ const float d=acc[ct][r]-mu_r[r]; pq += d*d; }
            scr[(kg*4+r)*16 + l15] = pq;
        }
        if (lane<16){
            float s=0.f;
#pragma unroll
            for (int i=0;i<4;i++){
                f32x4 v = *(const f32x4*)(scr + lane*16 + i*4);
                s += (v[0]+v[1])+(v[2]+v[3]);
            }
            scr[272+lane] = rsqrtf(s*(1.f/HD)+1e-5f);
        }
#pragma unroll
        for (int r=0;r<4;r++) rs_r[r] = scr[272+kg*4+r];
    }
    // x -> R0 (agg dead after s4 reads)
#pragma unroll
    for (int ct=0;ct<8;ct++){
        const int col=ct*16+l15;
        const float g = vng[col], bb = vnb[col];
#pragma unroll
        for (int r=0;r<4;r++){
            const int rl=kg*4+r;
            R0[rl*136 + col] = (f16)((acc[ct][r]-mu_r[r])*rs_r[r]*g + bb);
        }
    }

    // MLP h-half split: h_half -> R1 (scratch dead), y in acc_y
    f32x4 acc_y[8];
#pragma unroll
    for (int i=0;i<8;i++) acc_y[i]=(f32x4){0.f,0.f,0.f,0.f};
#pragma unroll
    for (int half=0; half<2; half++){
#pragma unroll
        for (int i=0;i<8;i++) acc[i]=(f32x4){0.f,0.f,0.f,0.f};
#pragma unroll
        for (int kb=0;kb<4;kb++){
            f16x8 af = *(const f16x8*)(R0 + l15*136 + kb*32 + kg*8);
#pragma unroll
            for (int ct=0;ct<8;ct++){
                const int ctp = half*8+ct;
                f16x8 bf = *(const f16x8*)(BPv1 + (((kb*16+ctp)*64+lane)<<3));
                acc[ct]=MFMA(af,bf,acc[ct]);
            }
        }
#pragma unroll
        for (int ct=0;ct<8;ct++){
            const int colg = half*128 + ct*16 + l15;
            const float bb = bv1[colg];
#pragma unroll
            for (int r=0;r<4;r++){
                const int rl=kg*4+r;
                R1[rl*136 + ct*16+l15] = (f16)gelu_f(acc[ct][r]+bb);
            }
        }
#pragma unroll
        for (int kb=0;kb<4;kb++){
            f16x8 af = *(const f16x8*)(R1 + l15*136 + kb*32 + kg*8);
#pragma unroll
            for (int ct=0;ct<8;ct++){
                f16x8 bf = *(const f16x8*)(BPv2 + ((((half*4+kb)*8+ct)*64+lane)<<3));
                acc_y[ct]=MFMA(af,bf,acc_y[ct]);
            }
        }
    }
    // y = x(R0) + acc_y + bv2 -> vout
#pragma unroll
    for (int ct=0;ct<8;ct++){
        const int col=ct*16+l15;
        const float bb=bv2[col];
#pragma unroll
        for (int r=0;r<4;r++){
            const int rl=kg*4+r;
            vout[(tile0+rl)*HD+col] = (float)R0[rl*136+col] + acc_y[ct][r] + bb;
        }
    }
}

// ---------------- k_hex4: same structure; own hexf rows staged f16 in R1
__global__ __launch_bounds__(256,4) void k_hex4(
    const float* __restrict__ hexf, const float* __restrict__ vfin,
    const int* __restrict__ h2v,
    const f16* __restrict__ BPdef, const float* __restrict__ b_def,
    const float* __restrict__ hng, const float* __restrict__ hnb,
    const f16* __restrict__ BPh1, const float* __restrict__ bh1,
    const f16* __restrict__ BPh2, const float* __restrict__ bh2,
    float* __restrict__ hout)
{
    __shared__ f16 lds[4*4352];
    const int tid=threadIdx.x, wave=tid>>6, lane=tid&63;
    const int l15=lane&15, kg=lane>>4;
    f16* R0 = lds + wave*4352;
    f16* R1 = R0 + 2176;
    float* scr = (float*)R1;
    const long tile0 = (long)(blockIdx.x*4+wave)*16;

    // s1: pooled mean -> R0, own hexf rows (f16) -> R1
#pragma unroll 4
    for (int r=0;r<16;r++){
        const long row = tile0 + r;
        const int b = (int)(row / NT);
        const int t = (int)(row - (long)b*NT);
        f32x2 ow = *(const f32x2*)(hexf + row*HD + lane*2);
        float s0=0.f, s1=0.f; int cnt=0;
#pragma unroll
        for (int j=0;j<6;j++){
            const int idx = h2v[t*6+j];
            if (idx>=0){
                cnt++;
                f32x2 p = *(const f32x2*)(vfin + ((long)(b*NN+idx)*HD + lane*2));
                s0 += p[0]; s1 += p[1];
            }
        }
        const float ic = 1.0f/(float)(cnt<1?1:cnt);
        *(f16x2*)(R0 + r*136 + lane*2) = (f16x2){(f16)(s0*ic),(f16)(s1*ic)};
        *(f16x2*)(R1 + r*136 + lane*2) = (f16x2){(f16)ow[0],(f16)ow[1]};
    }

    f32x4 acc[8];
    // s2: deflated = p @ W_def -> acc ; += b_def + residual(R1)
#pragma unroll
    for (int i=0;i<8;i++) acc[i]=(f32x4){0.f,0.f,0.f,0.f};
#pragma unroll
    for (int kb=0;kb<4;kb++){
        f16x8 af = *(const f16x8*)(R0 + l15*136 + kb*32 + kg*8);
#pragma unroll
        for (int ct=0;ct<8;ct++){
            f16x8 bf = *(const f16x8*)(BPdef + (((kb*8+ct)*64+lane)<<3));
            acc[ct]=MFMA(af,bf,acc[ct]);
        }
    }
#pragma unroll
    for (int ct=0;ct<8;ct++){
        const int col=ct*16+l15;
        const float bd = b_def[col];
#pragma unroll
        for (int r=0;r<4;r++)
            acc[ct][r] += bd + (float)R1[(kg*4+r)*136 + col];
    }
    // LN via scratch @R1 (stage dead)
    float mu_r[4], rs_r[4];
    {
#pragma unroll
        for (int r=0;r<4;r++){
            float ps=0.f;
#pragma unroll
            for (int ct=0;ct<8;ct++) ps += acc[ct][r];
            scr[(kg*4+r)*16 + l15] = ps;
        }
        if (lane<16){
            float s=0.f;
#pragma unroll
            for (int i=0;i<4;i++){
                f32x4 v = *(const f32x4*)(scr + lane*16 + i*4);
                s += (v[0]+v[1])+(v[2]+v[3]);
            }
            scr[256+lane] = s*(1.f/HD);
        }
#pragma unroll
        for (int r=0;r<4;r++) mu_r[r] = scr[256+kg*4+r];
#pragma unroll
        for (int r=0;r<4;r++){
            float pq=0.f;
#pragma unroll
            for (int ct=0;ct<8;ct++){ const float d=acc[ct][r]-mu_r[r]; pq += d*d; }
            scr[(kg*4+r)*16 + l15] = pq;
        }
        if (lane<16){
            float s=0.f;
#pragma unroll
            for (int i=0;i<4;i++){
                f32x4 v = *(const f32x4*)(scr + lane*16 + i*4);
                s += (v[0]+v[1])+(v[2]+v[3]);
            }
            scr[272+lane] = rsqrtf(s*(1.f/HD)+1e-5f);
        }
#pragma unroll
        for (int r=0;r<4;r++) rs_r[r] = scr[272+kg*4+r];
    }
    // x -> R0 (p dead)
#pragma unroll
    for (int ct=0;ct<8;ct++){
        const int col=ct*16+l15;
        const float g = hng[col], bb = hnb[col];
#pragma unroll
        for (int r=0;r<4;r++){
            const int rl=kg*4+r;
            R0[rl*136 + col] = (f16)((acc[ct][r]-mu_r[r])*rs_r[r]*g + bb);
        }
    }

    // MLP h-half split
    f32x4 acc_y[8];
#pragma unroll
    for (int i=0;i<8;i++) acc_y[i]=(f32x4){0.f,0.f,0.f,0.f};
#pragma unroll
    for (int half=0; half<2; half++){
#pragma unroll
        for (int i=0;i<8;i++) acc[i]=(f32x4){0.f,0.f,0.f,0.f};
#pragma unroll
        for (int kb=0;kb<4;kb++){
            f16x8 af = *(const f16x8*)(R0 + l15*136 + kb*32 + kg*8);
#pragma unroll
            for (int ct=0;ct<8;ct++){
                const int ctp = half*8+ct;
                f16x8 bf = *(const f16x8*)(BPh1 + (((kb*16+ctp)*64+lane)<<3));
                acc[ct]=MFMA(af,bf,acc[ct]);
            }
        }
#pragma unroll
        for (int ct=0;ct<8;ct++){
            const int colg = half*128 + ct*16 + l15;
            const float bb = bh1[colg];
#pragma unroll
            for (int r=0;r<4;r++){
                const int rl=kg*4+r;
                R1[rl*136 + ct*16+l15] = (f16)gelu_f(acc[ct][r]+bb);
            }
        }
#pragma unroll
        for (int kb=0;kb<4;kb++){
            f16x8 af = *(const f16x8*)(R1 + l15*136 + kb*32 + kg*8);
#pragma unroll
            for (int ct=0;ct<8;ct++){
                f16x8 bf = *(const f16x8*)(BPh2 + ((((half*4+kb)*8+ct)*64+lane)<<3));
                acc_y[ct]=MFMA(af,bf,acc_y[ct]);
            }
        }
    }
#pragma unroll
    for (int ct=0;ct<8;ct++){
        const int col=ct*16+l15;
        const float bb=bh2[col];
#pragma unroll
        for (int r=0;r<4;r++){
            const int rl=kg*4+r;
            hout[(tile0+rl)*HD+col] = (float)R0[rl*136+col] + acc_y[ct][r] + bb;
        }
    }
}

extern "C" void kernel_launch(void* const* d_in, const int* in_sizes, int n_in,
                              void* d_out, int out_size, void* d_ws, size_t ws_size,
                              hipStream_t stream)
{
    (void)in_sizes; (void)n_in; (void)out_size; (void)ws_size;
    const float* hexf  = (const float*)d_in[0];
    const float* vertf = (const float*)d_in[1];
    const float* W_inf = (const float*)d_in[2];
    const float* b_inf = (const float*)d_in[3];
    const float* W_msg = (const float*)d_in[4];
    const float* b_msg = (const float*)d_in[5];
    const float* W_upd = (const float*)d_in[6];
    const float* b_upd = (const float*)d_in[7];
    const float* W_def = (const float*)d_in[8];
    const float* b_def = (const float*)d_in[9];
    const float* vng   = (const float*)d_in[10];
    const float* vnb   = (const float*)d_in[11];
    const float* hng   = (const float*)d_in[12];
    const float* hnb   = (const float*)d_in[13];
    const float* Wv1   = (const float*)d_in[14];
    const float* bv1   = (const float*)d_in[15];
    const float* Wv2   = (const float*)d_in[16];
    const float* bv2   = (const float*)d_in[17];
    const float* Wh1   = (const float*)d_in[18];
    const float* bh1   = (const float*)d_in[19];
    const float* Wh2   = (const float*)d_in[20];
    const float* bh2   = (const float*)d_in[21];
    const int* v2h   = (const int*)d_in[22];
    const int* h2v   = (const int*)d_in[23];
    const int* vadj  = (const int*)d_in[24];

    const long NV = (long)NB*NN;                 // 240000 vertex rows
    f16* v1h = (f16*)d_ws;                       // 61.44 MB
    f16* packs = (f16*)((char*)d_ws + (size_t)NV*HD*2);
    f16* BPinf = packs;                // off 0       (384x128)
    f16* BPmsg = BPinf + 49152;        // off 49152   (128x128)
    f16* BPupd = BPmsg + 16384;        // off 65536   (256x128)
    f16* BPdef = BPupd + 32768;        // off 98304   (128x128)
    f16* BPv1  = BPdef + 16384;        // off 114688  (128x256)
    f16* BPv2  = BPv1 + 32768;         // off 147456  (256x128)
    f16* BPh1  = BPv2 + 32768;         // off 180224  (128x256)
    f16* BPh2  = BPh1 + 32768;         // off 212992  (256x128)

    PackArgs pa;
    pa.src[0]=W_inf; pa.K[0]=384; pa.Nc[0]=128; pa.off[0]=0;
    pa.src[1]=W_msg; pa.K[1]=128; pa.Nc[1]=128; pa.off[1]=49152;
    pa.src[2]=W_upd; pa.K[2]=256; pa.Nc[2]=128; pa.off[2]=65536;
    pa.src[3]=W_def; pa.K[3]=128; pa.Nc[3]=128; pa.off[3]=98304;
    pa.src[4]=Wv1;   pa.K[4]=128; pa.Nc[4]=256; pa.off[4]=114688;
    pa.src[5]=Wv2;   pa.K[5]=256; pa.Nc[5]=128; pa.off[5]=147456;
    pa.src[6]=Wh1;   pa.K[6]=128; pa.Nc[6]=256; pa.off[6]=180224;
    pa.src[7]=Wh2;   pa.K[7]=256; pa.Nc[7]=128; pa.off[7]=212992;
    k_pack_all<<<960,256,0,stream>>>(pa, packs);

    float* hout = (float*)d_out;
    float* vout = hout + (long)NB*NT*HD;

    k_inflate4<<<3750,256,0,stream>>>(hexf, vertf, v2h, BPinf, b_inf, v1h);
    k_vertex4<<<3750,256,0,stream>>>(v1h, vadj, BPmsg, b_msg, BPupd, b_upd,
                                     vng, vnb, BPv1, bv1, BPv2, bv2, vout);
    k_hex4<<<1250,256,0,stream>>>(hexf, vout, h2v, BPdef, b_def, hng, hnb,
                                  BPh1, bh1, BPh2, bh2, hout);
}